// Round 3
// baseline (787.116 us; speedup 1.0000x reference)
//
#include <hip/hip_runtime.h>
#include <hip/hip_bf16.h>
#include <math.h>

typedef __hip_bfloat16 bf16;
typedef __attribute__((ext_vector_type(8))) short short8;   // 8 bf16 = 4 VGPRs (MFMA A/B frag)
typedef __attribute__((ext_vector_type(4))) float f32x4;    // MFMA C/D frag

static constexpr int kB = 2;
static constexpr int kT = 2048;
static constexpr int kDIM = 1024;
static constexpr int kNMETA = 4;
static constexpr int kTEXT = kT + kNMETA;   // 2052
static constexpr int kMEXT = kB * kTEXT;    // 4104
static constexpr int kMPAD = 4160;          // 65*64, zero-padded rows for guard-free GEMM
static constexpr int kMX = kB * kT;         // 4096
static constexpr int kQT = 33;              // ceil(2052/64)

// ---------- workspace layout (bytes), high-water ~20.3 MB ----------
// Region XE [0, 8519680): x_ext bf16 [4160][1024] during QKV GEMMs; later YB bf16 [4096][1024]
static constexpr size_t oXE = 0;
static constexpr size_t oYB = 0;                                  // aliases XE (dead after GEMMs)
// Region QKV [8519680, 17039360): Q/K/V bf16 during attention; afterwards SSM intermediates
static constexpr size_t oQB = 8519680;                            // Q bf16 [4160][512]
static constexpr size_t oKB = oQB + (size_t)kMPAD * 512 * 2;      // K bf16 [4160][256]
static constexpr size_t oVB = oKB + (size_t)kMPAD * 256 * 2;      // V bf16 [4160][256]
static constexpr size_t oLA = oQB;                                // la f32 [4096][128]
static constexpr size_t oUU = oLA + (size_t)kMX * 128 * 4;        // u  f32
static constexpr size_t oCC = oUU + (size_t)kMX * 128 * 4;        // Cc f32
static constexpr size_t oHL = oCC + (size_t)kMX * 128 * 4;        // hloc bf16
static constexpr size_t oPB = oHL + (size_t)kMX * 128 * 2;        // P    bf16
static constexpr size_t oCH = oPB + (size_t)kMX * 128 * 2;        // chunk h  f32 [8192]
static constexpr size_t oCP = oCH + 8192 * 4;                     // chunk P  f32 [8192]
static constexpr size_t oH0 = oCP + 8192 * 4;                     // chunk h0 f32 [8192]
// Region SX [17039360, 21233664): ssm input bf16 [4096][512] (live whole SSM phase)
static constexpr size_t oSX = oVB + (size_t)kMPAD * 256 * 2;

__device__ __forceinline__ float bf2f(unsigned short u) {
  return __uint_as_float(((unsigned int)u) << 16);
}

// pack 8 f32 -> 8 bf16 (RNE) in a uint4
__device__ __forceinline__ uint4 pack8(float4 a, float4 b) {
  union { bf16 h[8]; uint4 v; } u;
  u.h[0] = __float2bfloat16(a.x); u.h[1] = __float2bfloat16(a.y);
  u.h[2] = __float2bfloat16(a.z); u.h[3] = __float2bfloat16(a.w);
  u.h[4] = __float2bfloat16(b.x); u.h[5] = __float2bfloat16(b.y);
  u.h[6] = __float2bfloat16(b.z); u.h[7] = __float2bfloat16(b.w);
  return u.v;
}

// ---------------- build x_ext = [meta ; x] (f32 -> bf16), zero-pad rows to 4160 -------------
__global__ __launch_bounds__(256) void build_xext(const float* __restrict__ x,
                                                  const float* __restrict__ meta,
                                                  bf16* __restrict__ xe) {
  int i = blockIdx.x * 256 + threadIdx.x;   // 8-elem group index
  int row = i >> 7, v = i & 127;
  if (row >= kMPAD) return;
  uint4 val = {0u, 0u, 0u, 0u};
  if (row < kMEXT) {
    int b = row / kTEXT, te = row - b * kTEXT;
    const float* src = (te < kNMETA) ? (meta + (size_t)te * kDIM)
                                     : (x + ((size_t)b * kT + (te - kNMETA)) * kDIM);
    float4 a0 = ((const float4*)src)[v * 2];
    float4 a1 = ((const float4*)src)[v * 2 + 1];
    val = pack8(a0, a1);
  }
  ((uint4*)(xe + (size_t)row * kDIM))[v] = val;
}

// ---------------- C[M,N] = A[M,K] @ W[N,K]^T ----------------
// A: bf16 or f32 (converted to bf16 at stage). W: f32 (converted at stage). out: bf16 or f32.
// 64x64 tile / block, 4 waves 2x2, each wave 32x32 via 2x2 mfma_f32_16x16x32_bf16.
template <bool A_IS_F32, bool OUT_IS_F32>
__global__ __launch_bounds__(256) void gemm_bt(const void* __restrict__ Av,
                                               const float* __restrict__ W,
                                               void* __restrict__ Cv, int N, int K) {
  __shared__ short As[64][40];   // 32 data + 8 pad shorts
  __shared__ short Bs[64][40];
  const int tid = threadIdx.x;
  const int wave = tid >> 6, lane = tid & 63;
  const int wr = wave >> 1, wc = wave & 1;
  const int quad = lane >> 4, l16 = lane & 15;
  const int bm = blockIdx.y * 64, bn = blockIdx.x * 64;
  const int srow = tid >> 2, scol = (tid & 3) * 8;
  f32x4 acc[2][2] = {};
  const float* wp = W + (size_t)(bn + srow) * K + scol;
  const float* afp = A_IS_F32 ? ((const float*)Av + (size_t)(bm + srow) * K + scol) : nullptr;
  const bf16*  abp = A_IS_F32 ? nullptr : ((const bf16*)Av + (size_t)(bm + srow) * K + scol);
  for (int k0 = 0; k0 < K; k0 += 32) {
    uint4 av, bv;
    if constexpr (A_IS_F32) {
      av = pack8(((const float4*)afp)[0], ((const float4*)afp)[1]);
      afp += 32;
    } else {
      av = *(const uint4*)abp;
      abp += 32;
    }
    bv = pack8(((const float4*)wp)[0], ((const float4*)wp)[1]);
    wp += 32;
    __syncthreads();            // prior-iter LDS reads done
    *(uint4*)&As[srow][scol] = av;
    *(uint4*)&Bs[srow][scol] = bv;
    __syncthreads();
    short8 af[2], bfr[2];
#pragma unroll
    for (int i = 0; i < 2; ++i) af[i] = *(const short8*)&As[wr * 32 + i * 16 + l16][quad * 8];
#pragma unroll
    for (int j = 0; j < 2; ++j) bfr[j] = *(const short8*)&Bs[wc * 32 + j * 16 + l16][quad * 8];
#pragma unroll
    for (int i = 0; i < 2; ++i)
#pragma unroll
      for (int j = 0; j < 2; ++j)
        acc[i][j] = __builtin_amdgcn_mfma_f32_16x16x32_bf16(af[i], bfr[j], acc[i][j], 0, 0, 0);
  }
#pragma unroll
  for (int i = 0; i < 2; ++i)
#pragma unroll
    for (int j = 0; j < 2; ++j) {
      int row0 = bm + wr * 32 + i * 16 + quad * 4;
      int col = bn + wc * 32 + j * 16 + l16;
#pragma unroll
      for (int r = 0; r < 4; ++r) {
        size_t off = (size_t)(row0 + r) * N + col;
        if constexpr (OUT_IS_F32) ((float*)Cv)[off] = acc[i][j][r];
        else                      ((bf16*)Cv)[off] = __float2bfloat16(acc[i][j][r]);
      }
    }
}

// ---------------- RMSnorm + RoPE (+q_gain) in-place on Q (8 heads) and K (4 kv heads) -------
__global__ __launch_bounds__(256) void norm_rope(bf16* __restrict__ Qb, bf16* __restrict__ Kb,
                                                 const float* __restrict__ q_gain) {
  int job = blockIdx.x * 4 + (threadIdx.x >> 6);
  if (job >= kMEXT * 12) return;
  int lane = threadIdx.x & 63;
  int row = job / 12, slot = job - row * 12;
  int te = row % kTEXT;
  float gain = 1.f;
  bf16* buf;
  if (slot < 8) { buf = Qb + (size_t)row * 512 + slot * 64; gain = q_gain[slot]; }
  else          { buf = Kb + (size_t)row * 256 + (slot - 8) * 64; }
  float v = __bfloat162float(buf[lane]);
  float ss = v * v;
#pragma unroll
  for (int o = 32; o > 0; o >>= 1) ss += __shfl_xor(ss, o, 64);
  float vn = v * (1.f / sqrtf(ss * (1.f / 64.f) + 1e-6f));
  float p = __shfl_xor(vn, 32, 64);
  // inv = 10000^(-(lane&31)/32) ; angle = te * inv
  float ang = (float)te * exp2f(-13.287712379549449f * (float)(lane & 31) * (1.f / 32.f));
  float c = cosf(ang), s = sinf(ang);
  float outv = (lane < 32) ? (vn * c - p * s) : (p * s + vn * c);
  buf[lane] = __float2bfloat16(outv * gain);
}

// ---------------- causal flash attention, f32 compute, bf16 Q/K/V, 64-query tiles ----------
// block = 256 threads: thread (r = tid>>2, g = tid&3); scores for keys 4*j+g; out dims g*16..
__global__ __launch_bounds__(256) void attn_fwd(const bf16* __restrict__ Qb,
                                                const bf16* __restrict__ Kb,
                                                const bf16* __restrict__ Vb,
                                                const float* __restrict__ attn_scale,
                                                bf16* __restrict__ Y) {
  __shared__ float Qs[64][68], KsPs[64][68], Vs[64][68];   // KsPs reused: K-tile then P
  __shared__ float Smax[64][4], Ssum[64][4];
  const int qt = (kQT - 1) - blockIdx.x;       // longest blocks first
  const int h = blockIdx.y, b = blockIdx.z;
  const int kvh = h >> 1;
  const int tid = threadIdx.x, r = tid >> 2, g = tid & 3;
  const int te_q = qt * 64 + r;
  {
    bool ok = te_q < kTEXT;
    int te = ok ? te_q : 0;
    const ushort* qr = (const ushort*)(Qb + ((size_t)b * kTEXT + te) * 512 + h * 64 + g * 16);
    uint4 raw0 = ((const uint4*)qr)[0], raw1 = ((const uint4*)qr)[1];
    const ushort* p0 = (const ushort*)&raw0;
    const ushort* p1 = (const ushort*)&raw1;
#pragma unroll
    for (int i = 0; i < 8; ++i) {
      Qs[r][g * 16 + i]     = ok ? bf2f(p0[i]) : 0.f;
      Qs[r][g * 16 + 8 + i] = ok ? bf2f(p1[i]) : 0.f;
    }
  }
  float m = -1e30f, l = 0.f;
  float o[16];
#pragma unroll
  for (int c = 0; c < 16; ++c) o[c] = 0.f;
  for (int kt = 0; kt <= qt; ++kt) {
    __syncthreads();   // prior-iter LDS reads done (also covers the Q store on kt=0)
    {
      int te_k = kt * 64 + r;
      bool ok = te_k < kTEXT;
      int te = ok ? te_k : 0;
      const ushort* kr = (const ushort*)(Kb + ((size_t)b * kTEXT + te) * 256 + kvh * 64 + g * 16);
      const ushort* vr = (const ushort*)(Vb + ((size_t)b * kTEXT + te) * 256 + kvh * 64 + g * 16);
      uint4 k0 = ((const uint4*)kr)[0], k1 = ((const uint4*)kr)[1];
      uint4 v0 = ((const uint4*)vr)[0], v1 = ((const uint4*)vr)[1];
      const ushort* a0 = (const ushort*)&k0; const ushort* a1 = (const ushort*)&k1;
      const ushort* b0 = (const ushort*)&v0; const ushort* b1 = (const ushort*)&v1;
#pragma unroll
      for (int i = 0; i < 8; ++i) {
        KsPs[r][g * 16 + i]     = ok ? bf2f(a0[i]) : 0.f;
        KsPs[r][g * 16 + 8 + i] = ok ? bf2f(a1[i]) : 0.f;
        Vs[r][g * 16 + i]       = ok ? bf2f(b0[i]) : 0.f;
        Vs[r][g * 16 + 8 + i]   = ok ? bf2f(b1[i]) : 0.f;
      }
    }
    __syncthreads();
    float sc[16];
#pragma unroll
    for (int j = 0; j < 16; ++j) sc[j] = 0.f;
#pragma unroll 4
    for (int d4 = 0; d4 < 16; ++d4) {
      float4 q4 = *(const float4*)&Qs[r][d4 * 4];
#pragma unroll
      for (int j = 0; j < 16; ++j) {
        float4 k4 = *(const float4*)&KsPs[4 * j + g][d4 * 4];
        sc[j] += q4.x * k4.x + q4.y * k4.y + q4.z * k4.z + q4.w * k4.w;
      }
    }
    float tmax = -1e30f;
#pragma unroll
    for (int j = 0; j < 16; ++j) {
      int key = kt * 64 + 4 * j + g;
      sc[j] = (key <= te_q) ? sc[j] * 0.125f : -1e30f;
      tmax = fmaxf(tmax, sc[j]);
    }
    Smax[r][g] = tmax;
    __syncthreads();   // also: all K reads done -> KsPs reusable as P
    float mn = fmaxf(fmaxf(Smax[r][0], Smax[r][1]), fmaxf(Smax[r][2], Smax[r][3]));
    mn = fmaxf(m, mn);
    float psum = 0.f;
#pragma unroll
    for (int j = 0; j < 16; ++j) {
      float pv = expf(sc[j] - mn);   // masked: exp(-1e30 - mn) == 0, never NaN
      psum += pv;
      KsPs[r][4 * j + g] = pv;
    }
    Ssum[r][g] = psum;
    __syncthreads();
    float alpha = expf(m - mn);
    l = l * alpha + Ssum[r][0] + Ssum[r][1] + Ssum[r][2] + Ssum[r][3];
    m = mn;
#pragma unroll
    for (int c = 0; c < 16; ++c) o[c] *= alpha;
    for (int k = 0; k < 64; ++k) {
      float pv = KsPs[r][k];
#pragma unroll
      for (int q4 = 0; q4 < 4; ++q4) {
        float4 vv = *(const float4*)&Vs[k][g * 16 + q4 * 4];
        o[q4 * 4 + 0] += pv * vv.x; o[q4 * 4 + 1] += pv * vv.y;
        o[q4 * 4 + 2] += pv * vv.z; o[q4 * 4 + 3] += pv * vv.w;
      }
    }
  }
  if (te_q >= kNMETA && te_q < kTEXT) {
    float so = attn_scale[0] / fmaxf(l, 1e-30f);
    bf16* dst = Y + ((size_t)b * kT + (te_q - kNMETA)) * kDIM + h * 64 + g * 16;
#pragma unroll
    for (int c = 0; c < 16; ++c) dst[c] = __float2bfloat16(o[c] * so);
  }
}

// ---------------- SSM: dt / la / u / Cc per (b,t,h,s) ----------------
__global__ __launch_bounds__(256) void ssm_prep(const bf16* __restrict__ sx,
                                                const float* __restrict__ dtw, const float* __restrict__ dtb,
                                                const float* __restrict__ Bw, const float* __restrict__ Cw,
                                                const float* __restrict__ logA,
                                                float* __restrict__ la, float* __restrict__ u,
                                                float* __restrict__ Cc) {
  int idx = blockIdx.x * 256 + threadIdx.x;
  if (idx >= kMX * 128) return;
  int s = idx & 15, h = (idx >> 4) & 7, bt = idx >> 7;
  const bf16* xp = sx + (size_t)bt * 512 + h * 64;
  const float* wd = dtw + (h * 16 + s) * 64;
  const float* wb = Bw + (h * 16 + s) * 64;
  const float* wc = Cw + (h * 16 + s) * 64;
  float dd = 0.f, db = 0.f, dc = 0.f;
#pragma unroll 8
  for (int d = 0; d < 64; ++d) {
    float xv = __bfloat162float(xp[d]);
    dd += xv * wd[d];
    db += xv * wb[d];
    dc += xv * wc[d];
  }
  float raw = dd + dtb[h * 16 + s];
  float sp = fmaxf(raw, 0.f) + log1pf(expf(-fabsf(raw)));   // stable softplus
  float dt = fminf(sp, 1.f);
  float A = fminf(-expf(logA[h * 16 + s]), 10.f);
  float lav = fminf(fmaxf(dt * A, -0.5f), 0.f);
  la[idx] = lav;
  u[idx] = db * dt;
  Cc[idx] = dc;
}

// phase 1: per (b,h,s,chunk): local scan (h0=0) + running P=exp(clip(cumsum la,-30,0))
__global__ __launch_bounds__(256) void ssm_scan1(const float* __restrict__ la, const float* __restrict__ u,
                                                 bf16* __restrict__ hloc, bf16* __restrict__ Pb,
                                                 float* __restrict__ chH, float* __restrict__ chP) {
  int id = blockIdx.x * 256 + threadIdx.x;   // id = b*4096 + c*128 + h*16 + s
  if (id >= 8192) return;
  int hs = id & 127, c = (id >> 7) & 31, b = id >> 12;
  float hv = 0.f, cum = 0.f;
  size_t base = ((size_t)b * kT) * 128 + hs;
  for (int i = 0; i < 64; ++i) {
    size_t ix = base + (size_t)(c * 64 + i) * 128;
    float lav = la[ix], uv = u[ix];
    cum += lav;
    hv = expf(lav) * hv + uv;
    hloc[ix] = __float2bfloat16(hv);
    Pb[ix] = __float2bfloat16(expf(fmaxf(cum, -30.f)));
  }
  chH[id] = hv;
  chP[id] = expf(fmaxf(cum, -30.f));
}

// phase 2: cross-chunk prefix (256 chains, 32 chunks)
__global__ __launch_bounds__(256) void ssm_scan2(const float* __restrict__ chH,
                                                 const float* __restrict__ chP,
                                                 float* __restrict__ h0) {
  int id = threadIdx.x;     // (b, h*16+s)
  int b = id >> 7, hs = id & 127;
  float h0v = 0.f;
  for (int c = 0; c < 32; ++c) {
    int ci = b * 4096 + c * 128 + hs;
    h0[ci] = h0v;
    h0v = chH[ci] + chP[ci] * h0v;
  }
}

// phase 3: h = hloc + P*h0 ; y = sum Cc*h ; out = h@Ow^T + y*x0 ; write bf16 to Y[:,512:]
__global__ __launch_bounds__(256) void ssm_out(const bf16* __restrict__ hloc, const bf16* __restrict__ Pb,
                                               const float* __restrict__ h0, const float* __restrict__ Cc,
                                               const bf16* __restrict__ sx, const float* __restrict__ Ow,
                                               const float* __restrict__ ssm_scale, bf16* __restrict__ Y) {
  int id = blockIdx.x * 256 + threadIdx.x;   // (b,t,h)
  if (id >= kMX * 8) return;
  int h = id & 7, t = (id >> 3) & 2047, b = id >> 14;
  size_t ix0 = ((size_t)(b * kT + t)) * 128 + h * 16;
  int h0b = b * 4096 + (t >> 6) * 128 + h * 16;
  float hv[16], y = 0.f;
#pragma unroll
  for (int s = 0; s < 16; ++s) {
    float v = __bfloat162float(hloc[ix0 + s]) + __bfloat162float(Pb[ix0 + s]) * h0[h0b + s];
    hv[s] = v;
    y += Cc[ix0 + s] * v;
  }
  float x0 = __bfloat162float(sx[((size_t)(b * kT + t)) * 512 + h * 64]);
  float scl = ssm_scale[0];
  const float* ow = Ow + (size_t)h * 64 * 16;
  bf16* dst = Y + ((size_t)(b * kT + t)) * kDIM + 512 + h * 64;
  for (int d = 0; d < 64; ++d) {
    float acc = y * x0;
    const float* owr = ow + d * 16;
#pragma unroll
    for (int s = 0; s < 16; ++s) acc += hv[s] * owr[s];
    dst[d] = __float2bfloat16(acc * scl);
  }
}

// ---------------- host ----------------
extern "C" void kernel_launch(void* const* d_in, const int* in_sizes, int n_in,
                              void* d_out, int out_size, void* d_ws, size_t ws_size,
                              hipStream_t stream) {
  (void)in_sizes; (void)n_in; (void)out_size; (void)ws_size;
  const float* x        = (const float*)d_in[0];
  const float* meta     = (const float*)d_in[1];
  const float* c_q_w    = (const float*)d_in[2];
  const float* c_k_w    = (const float*)d_in[3];
  const float* c_v_w    = (const float*)d_in[4];
  const float* q_gain   = (const float*)d_in[5];
  const float* ssm_in_w = (const float*)d_in[6];
  const float* proj_w   = (const float*)d_in[7];
  const float* attn_sc  = (const float*)d_in[8];
  const float* ssm_sc   = (const float*)d_in[9];
  const float* ssm_logA = (const float*)d_in[10];
  const float* ssm_Bw   = (const float*)d_in[11];
  const float* ssm_Cw   = (const float*)d_in[12];
  const float* ssm_dtw  = (const float*)d_in[13];
  const float* ssm_dtb  = (const float*)d_in[14];
  const float* ssm_Ow   = (const float*)d_in[15];

  char* w = (char*)d_ws;
  bf16*  XE = (bf16*)(w + oXE);
  bf16*  QB = (bf16*)(w + oQB);
  bf16*  KB = (bf16*)(w + oKB);
  bf16*  VB = (bf16*)(w + oVB);
  bf16*  SX = (bf16*)(w + oSX);
  bf16*  YB = (bf16*)(w + oYB);
  float* LA = (float*)(w + oLA);
  float* UU = (float*)(w + oUU);
  float* CC = (float*)(w + oCC);
  bf16*  HL = (bf16*)(w + oHL);
  bf16*  PB = (bf16*)(w + oPB);
  float* CH = (float*)(w + oCH);
  float* CP = (float*)(w + oCP);
  float* H0 = (float*)(w + oH0);

  build_xext<<<(kMPAD * 128 + 255) / 256, 256, 0, stream>>>(x, meta, XE);

  gemm_bt<false, false><<<dim3(8, kMPAD / 64), 256, 0, stream>>>(XE, c_q_w, QB, 512, 1024);  // Q heads 0..7
  gemm_bt<false, false><<<dim3(4, kMPAD / 64), 256, 0, stream>>>(XE, c_k_w, KB, 256, 1024);
  gemm_bt<false, false><<<dim3(4, kMPAD / 64), 256, 0, stream>>>(XE, c_v_w, VB, 256, 1024);
  gemm_bt<true,  false><<<dim3(8, kMX / 64), 256, 0, stream>>>(x, ssm_in_w, SX, 512, 1024);

  norm_rope<<<(kMEXT * 12 + 3) / 4, 256, 0, stream>>>(QB, KB, q_gain);
  // attn writes YB (aliases XE — XE dead after the GEMMs above)
  attn_fwd<<<dim3(kQT, 8, kB), 256, 0, stream>>>(QB, KB, VB, attn_sc, YB);

  // SSM intermediates alias Q/K/V — dead after attn_fwd
  ssm_prep<<<(kMX * 128 + 255) / 256, 256, 0, stream>>>(SX, ssm_dtw, ssm_dtb, ssm_Bw, ssm_Cw,
                                                        ssm_logA, LA, UU, CC);
  ssm_scan1<<<32, 256, 0, stream>>>(LA, UU, HL, PB, CH, CP);
  ssm_scan2<<<1, 256, 0, stream>>>(CH, CP, H0);
  ssm_out<<<(kMX * 8 + 255) / 256, 256, 0, stream>>>(HL, PB, H0, CC, SX, ssm_Ow, ssm_sc, YB);

  gemm_bt<false, true><<<dim3(16, kMX / 64), 256, 0, stream>>>(YB, proj_w, d_out, 1024, 1024);
}

// Round 4
// 395.772 us; speedup vs baseline: 1.9888x; 1.9888x over previous
//
#include <hip/hip_runtime.h>
#include <hip/hip_bf16.h>
#include <math.h>

typedef __hip_bfloat16 bf16;
typedef __attribute__((ext_vector_type(8))) short short8;   // 8 bf16 = 4 VGPRs (MFMA A/B frag)
typedef __attribute__((ext_vector_type(4))) float f32x4;    // MFMA C/D frag

static constexpr int kB = 2;
static constexpr int kT = 2048;
static constexpr int kDIM = 1024;
static constexpr int kNMETA = 4;
static constexpr int kTEXT = kT + kNMETA;   // 2052
static constexpr int kMEXT = kB * kTEXT;    // 4104
static constexpr int kMPAD = 4160;          // 65*64, zero-padded rows for guard-free GEMM
static constexpr int kMX = kB * kT;         // 4096
static constexpr int kQT = 33;              // ceil(2052/64)
static constexpr int kTP = 2112;            // 33*64 padded sequence length

// ---------- workspace layout (bytes), high-water ~29.9 MB ----------
static constexpr size_t oXE = 0;                                  // x_ext bf16 [4160][1024]
static constexpr size_t oYB = 0;                                  // aliases XE (dead after GEMMs)
static constexpr size_t oQB = 8519680;                            // Q bf16 [4160][512]
static constexpr size_t oKB = oQB + (size_t)kMPAD * 512 * 2;      // K bf16 [4160][256]
static constexpr size_t oVB = oKB + (size_t)kMPAD * 256 * 2;      // V bf16 [4160][256]
// SSM intermediates alias QB/KB/VB after attention:
static constexpr size_t oLA = oQB;                                // la f32 [4096][128]
static constexpr size_t oUU = oLA + (size_t)kMX * 128 * 4;
static constexpr size_t oCC = oUU + (size_t)kMX * 128 * 4;
static constexpr size_t oHL = oCC + (size_t)kMX * 128 * 4;        // hloc bf16
static constexpr size_t oPB = oHL + (size_t)kMX * 128 * 2;        // P    bf16
static constexpr size_t oCH = oPB + (size_t)kMX * 128 * 2;        // chunk h  f32 [8192]
static constexpr size_t oCP = oCH + 8192 * 4;
static constexpr size_t oH0 = oCP + 8192 * 4;
static constexpr size_t oSX = oVB + (size_t)kMPAD * 256 * 2;      // ssm x bf16 [4096][512]
// packed attention operands:
static constexpr size_t oQP = oSX + (size_t)kMX * 512 * 2;        // Qp bf16 [b][8][2112][64]
static constexpr size_t oKP = oQP + (size_t)kB * 8 * kTP * 64 * 2;// Kp bf16 [b][4][2112][64]
static constexpr size_t oVT = oKP + (size_t)kB * 4 * kTP * 64 * 2;// Vt bf16 [b][4][64][2112]

__device__ __forceinline__ float bf2f(unsigned short u) {
  return __uint_as_float(((unsigned int)u) << 16);
}

// pack 8 f32 -> 8 bf16 (RNE) in a uint4
__device__ __forceinline__ uint4 pack8(float4 a, float4 b) {
  union { bf16 h[8]; uint4 v; } u;
  u.h[0] = __float2bfloat16(a.x); u.h[1] = __float2bfloat16(a.y);
  u.h[2] = __float2bfloat16(a.z); u.h[3] = __float2bfloat16(a.w);
  u.h[4] = __float2bfloat16(b.x); u.h[5] = __float2bfloat16(b.y);
  u.h[6] = __float2bfloat16(b.z); u.h[7] = __float2bfloat16(b.w);
  return u.v;
}

// ---------------- build x_ext = [meta ; x] (f32 -> bf16), zero-pad rows to 4160 -------------
__global__ __launch_bounds__(256) void build_xext(const float* __restrict__ x,
                                                  const float* __restrict__ meta,
                                                  bf16* __restrict__ xe) {
  int i = blockIdx.x * 256 + threadIdx.x;
  int row = i >> 7, v = i & 127;
  if (row >= kMPAD) return;
  uint4 val = {0u, 0u, 0u, 0u};
  if (row < kMEXT) {
    int b = row / kTEXT, te = row - b * kTEXT;
    const float* src = (te < kNMETA) ? (meta + (size_t)te * kDIM)
                                     : (x + ((size_t)b * kT + (te - kNMETA)) * kDIM);
    float4 a0 = ((const float4*)src)[v * 2];
    float4 a1 = ((const float4*)src)[v * 2 + 1];
    val = pack8(a0, a1);
  }
  ((uint4*)(xe + (size_t)row * kDIM))[v] = val;
}

// ---------------- C[M,N] = A[M,K] @ W[N,K]^T (bf16 MFMA) ----------------
template <bool A_IS_F32, bool OUT_IS_F32>
__global__ __launch_bounds__(256) void gemm_bt(const void* __restrict__ Av,
                                               const float* __restrict__ W,
                                               void* __restrict__ Cv, int N, int K) {
  __shared__ short As[64][40];
  __shared__ short Bs[64][40];
  const int tid = threadIdx.x;
  const int wave = tid >> 6, lane = tid & 63;
  const int wr = wave >> 1, wc = wave & 1;
  const int quad = lane >> 4, l16 = lane & 15;
  const int bm = blockIdx.y * 64, bn = blockIdx.x * 64;
  const int srow = tid >> 2, scol = (tid & 3) * 8;
  f32x4 acc[2][2] = {};
  const float* wp = W + (size_t)(bn + srow) * K + scol;
  const float* afp = A_IS_F32 ? ((const float*)Av + (size_t)(bm + srow) * K + scol) : nullptr;
  const bf16*  abp = A_IS_F32 ? nullptr : ((const bf16*)Av + (size_t)(bm + srow) * K + scol);
  for (int k0 = 0; k0 < K; k0 += 32) {
    uint4 av, bv;
    if constexpr (A_IS_F32) {
      av = pack8(((const float4*)afp)[0], ((const float4*)afp)[1]);
      afp += 32;
    } else {
      av = *(const uint4*)abp;
      abp += 32;
    }
    bv = pack8(((const float4*)wp)[0], ((const float4*)wp)[1]);
    wp += 32;
    __syncthreads();
    *(uint4*)&As[srow][scol] = av;
    *(uint4*)&Bs[srow][scol] = bv;
    __syncthreads();
    short8 af[2], bfr[2];
#pragma unroll
    for (int i = 0; i < 2; ++i) af[i] = *(const short8*)&As[wr * 32 + i * 16 + l16][quad * 8];
#pragma unroll
    for (int j = 0; j < 2; ++j) bfr[j] = *(const short8*)&Bs[wc * 32 + j * 16 + l16][quad * 8];
#pragma unroll
    for (int i = 0; i < 2; ++i)
#pragma unroll
      for (int j = 0; j < 2; ++j)
        acc[i][j] = __builtin_amdgcn_mfma_f32_16x16x32_bf16(af[i], bfr[j], acc[i][j], 0, 0, 0);
  }
#pragma unroll
  for (int i = 0; i < 2; ++i)
#pragma unroll
    for (int j = 0; j < 2; ++j) {
      int row0 = bm + wr * 32 + i * 16 + quad * 4;
      int col = bn + wc * 32 + j * 16 + l16;
#pragma unroll
      for (int r = 0; r < 4; ++r) {
        size_t off = (size_t)(row0 + r) * N + col;
        if constexpr (OUT_IS_F32) ((float*)Cv)[off] = acc[i][j][r];
        else                      ((bf16*)Cv)[off] = __float2bfloat16(acc[i][j][r]);
      }
    }
}

// ------- RMSnorm + RoPE (+q_gain, +1/sqrt(D)) -> packed Qp[b][8][2112][64], Kp[b][4][2112][64]
__global__ __launch_bounds__(256) void norm_rope_pack(const bf16* __restrict__ QB,
                                                      const bf16* __restrict__ KB,
                                                      const float* __restrict__ q_gain,
                                                      bf16* __restrict__ Qp, bf16* __restrict__ Kp) {
  int job = blockIdx.x * 4 + (threadIdx.x >> 6);
  if (job >= kB * kTP * 12) return;
  int lane = threadIdx.x & 63;
  int slot = job % 12, rowp = job / 12;
  int b = rowp / kTP, te = rowp % kTP;
  bf16* dst = (slot < 8) ? Qp + (((size_t)(b * 8 + slot)) * kTP + te) * 64 + lane
                         : Kp + (((size_t)(b * 4 + slot - 8)) * kTP + te) * 64 + lane;
  if (te >= kTEXT) { *dst = __float2bfloat16(0.f); return; }
  const bf16* src = (slot < 8) ? QB + ((size_t)(b * kTEXT + te)) * 512 + slot * 64 + lane
                               : KB + ((size_t)(b * kTEXT + te)) * 256 + (slot - 8) * 64 + lane;
  float v = __bfloat162float(*src);
  float ss = v * v;
#pragma unroll
  for (int o = 32; o > 0; o >>= 1) ss += __shfl_xor(ss, o, 64);
  float vn = v * (1.f / sqrtf(ss * (1.f / 64.f) + 1e-6f));
  float p = __shfl_xor(vn, 32, 64);
  float ang = (float)te * exp2f(-13.287712379549449f * (float)(lane & 31) * (1.f / 32.f));
  float c = cosf(ang), s = sinf(ang);
  float outv = (lane < 32) ? (vn * c - p * s) : (p * s + vn * c);
  float gain = (slot < 8) ? q_gain[slot] * 0.125f : 1.f;
  *dst = __float2bfloat16(outv * gain);
}

// ------- V transpose: VB[row][256] -> Vt[b][kvh][64][2112] (zero pads), LDS-tiled -------
__global__ __launch_bounds__(256) void vrepack(const bf16* __restrict__ VB, bf16* __restrict__ Vt) {
  __shared__ short Ts[64][66];
  const int tt = blockIdx.x, kvh = blockIdx.y, b = blockIdx.z;
  const int tid = threadIdx.x;
#pragma unroll
  for (int r = 0; r < 2; ++r) {
    int e = r * 256 + tid, row = e >> 3, c8 = e & 7;
    int te = tt * 64 + row;
    uint4 val = {0u, 0u, 0u, 0u};
    if (te < kTEXT) val = *(const uint4*)(VB + ((size_t)(b * kTEXT + te)) * 256 + kvh * 64 + c8 * 8);
    union { uint4 u; short s[8]; } w; w.u = val;
#pragma unroll
    for (int i = 0; i < 8; ++i) Ts[row][c8 * 8 + i] = w.s[i];
  }
  __syncthreads();
#pragma unroll
  for (int r = 0; r < 2; ++r) {
    int e = r * 256 + tid, d = e >> 3, c8 = e & 7;
    union { uint4 u; short s[8]; } w;
#pragma unroll
    for (int i = 0; i < 8; ++i) w.s[i] = Ts[c8 * 8 + i][d];
    *(uint4*)(Vt + (((size_t)(b * 4 + kvh)) * 64 + d) * kTP + tt * 64 + c8 * 8) = w.u;
  }
}

// ---------------- MFMA causal flash attention ----------------
// block: 64 q-rows (4 waves x 16), loops over 64-key tiles. QK^T and PV via 16x16x32 bf16 MFMA.
__global__ __launch_bounds__(256) void attn_mfma(const bf16* __restrict__ Qp,
                                                 const bf16* __restrict__ Kp,
                                                 const bf16* __restrict__ Vt,
                                                 const float* __restrict__ attn_scale,
                                                 bf16* __restrict__ Y) {
  __shared__ short Ks[64][72];        // K tile [key][d], stride 72 -> uniform b128 bank spans
  __shared__ short Vs[64][72];        // V^T tile [d][key]
  __shared__ short Ps[4][16][68];     // per-wave P [q][key]
  const int qt = (kQT - 1) - blockIdx.x;   // longest first
  const int h = blockIdx.y, b = blockIdx.z;
  const int kvh = h >> 1;
  const int tid = threadIdx.x, wave = tid >> 6, lane = tid & 63;
  const int quad = lane >> 4, l16 = lane & 15;

  // Q A-frags in registers for the whole kernel (scale+gain pre-folded)
  short8 qf[2];
  {
    const bf16* qrow = Qp + (((size_t)(b * 8 + h)) * kTP + qt * 64 + wave * 16 + l16) * 64 + quad * 8;
    qf[0] = *(const short8*)(qrow);
    qf[1] = *(const short8*)(qrow + 32);
  }
  const bf16* kbase = Kp + ((size_t)(b * 4 + kvh)) * kTP * 64;
  const bf16* vbase = Vt + ((size_t)(b * 4 + kvh)) * 64 * kTP;

  f32x4 O[4] = {};
  float m_i[4], l_i[4];
#pragma unroll
  for (int r = 0; r < 4; ++r) { m_i[r] = -1e30f; l_i[r] = 0.f; }

  for (int kt = 0; kt <= qt; ++kt) {
    __syncthreads();   // prior-iter LDS reads done
#pragma unroll
    for (int r = 0; r < 2; ++r) {
      int e = r * 256 + tid, row = e >> 3, c8 = e & 7;
      uint4 kv = *(const uint4*)(kbase + ((size_t)(kt * 64 + row)) * 64 + c8 * 8);
      *(uint4*)&Ks[row][c8 * 8] = kv;
      uint4 vv = *(const uint4*)(vbase + (size_t)row * kTP + kt * 64 + c8 * 8);
      *(uint4*)&Vs[row][c8 * 8] = vv;
    }
    __syncthreads();

    // ---- QK^T: 16q x 64key per wave ----
    f32x4 sc[4] = {};
#pragma unroll
    for (int nb = 0; nb < 4; ++nb) {
      short8 bk0 = *(const short8*)&Ks[nb * 16 + l16][quad * 8];
      sc[nb] = __builtin_amdgcn_mfma_f32_16x16x32_bf16(qf[0], bk0, sc[nb], 0, 0, 0);
      short8 bk1 = *(const short8*)&Ks[nb * 16 + l16][32 + quad * 8];
      sc[nb] = __builtin_amdgcn_mfma_f32_16x16x32_bf16(qf[1], bk1, sc[nb], 0, 0, 0);
    }
    // ---- causal mask (diagonal tile only; 1/sqrt(D) folded into Q) ----
    if (kt == qt) {
      int te_q0 = qt * 64 + wave * 16 + quad * 4;
      int key = kt * 64 + l16;
#pragma unroll
      for (int nb = 0; nb < 4; ++nb)
#pragma unroll
        for (int rg = 0; rg < 4; ++rg)
          if (key + nb * 16 > te_q0 + rg) sc[nb][rg] = -1e30f;
    }
    // ---- online softmax ----
    float rmax[4];
#pragma unroll
    for (int rg = 0; rg < 4; ++rg)
      rmax[rg] = fmaxf(fmaxf(sc[0][rg], sc[1][rg]), fmaxf(sc[2][rg], sc[3][rg]));
#pragma unroll
    for (int rg = 0; rg < 4; ++rg) {
#pragma unroll
      for (int off = 1; off < 16; off <<= 1)
        rmax[rg] = fmaxf(rmax[rg], __shfl_xor(rmax[rg], off, 64));
    }
    float al[4];
#pragma unroll
    for (int rg = 0; rg < 4; ++rg) {
      float mn = fmaxf(m_i[rg], rmax[rg]);
      al[rg] = __expf(m_i[rg] - mn);
      m_i[rg] = mn;
    }
    float ps[4] = {0.f, 0.f, 0.f, 0.f};
#pragma unroll
    for (int nb = 0; nb < 4; ++nb)
#pragma unroll
      for (int rg = 0; rg < 4; ++rg) {
        float p = __expf(sc[nb][rg] - m_i[rg]);
        ps[rg] += p;
        *(bf16*)&Ps[wave][quad * 4 + rg][nb * 16 + l16] = __float2bfloat16(p);
      }
#pragma unroll
    for (int rg = 0; rg < 4; ++rg) {
#pragma unroll
      for (int off = 1; off < 16; off <<= 1) ps[rg] += __shfl_xor(ps[rg], off, 64);
      l_i[rg] = l_i[rg] * al[rg] + ps[rg];
    }
#pragma unroll
    for (int db = 0; db < 4; ++db)
#pragma unroll
      for (int rg = 0; rg < 4; ++rg) O[db][rg] *= al[rg];

    // ---- PV: P A-frags from wave-private LDS (no barrier needed) ----
    union { short8 v; unsigned long long q[2]; } pf0, pf1;
    {
      const char* pb = (const char*)&Ps[wave][l16][0] + quad * 16;
      pf0.q[0] = *(const unsigned long long*)(pb);
      pf0.q[1] = *(const unsigned long long*)(pb + 8);
      pf1.q[0] = *(const unsigned long long*)(pb + 64);
      pf1.q[1] = *(const unsigned long long*)(pb + 72);
    }
#pragma unroll
    for (int db = 0; db < 4; ++db) {
      short8 bv0 = *(const short8*)&Vs[db * 16 + l16][quad * 8];
      O[db] = __builtin_amdgcn_mfma_f32_16x16x32_bf16(pf0.v, bv0, O[db], 0, 0, 0);
      short8 bv1 = *(const short8*)&Vs[db * 16 + l16][32 + quad * 8];
      O[db] = __builtin_amdgcn_mfma_f32_16x16x32_bf16(pf1.v, bv1, O[db], 0, 0, 0);
    }
  }
  // ---- epilogue ----
  float asc = attn_scale[0];
#pragma unroll
  for (int rg = 0; rg < 4; ++rg) {
    int te_q = qt * 64 + wave * 16 + quad * 4 + rg;
    if (te_q < kNMETA || te_q >= kTEXT) continue;
    float so = asc / fmaxf(l_i[rg], 1e-30f);
    bf16* dst = Y + ((size_t)(b * kT + te_q - kNMETA)) * kDIM + h * 64 + l16;
#pragma unroll
    for (int db = 0; db < 4; ++db) dst[db * 16] = __float2bfloat16(O[db][rg] * so);
  }
}

// ---------------- SSM: dt / la / u / Cc per (b,t,h,s) ----------------
__global__ __launch_bounds__(256) void ssm_prep(const bf16* __restrict__ sx,
                                                const float* __restrict__ dtw, const float* __restrict__ dtb,
                                                const float* __restrict__ Bw, const float* __restrict__ Cw,
                                                const float* __restrict__ logA,
                                                float* __restrict__ la, float* __restrict__ u,
                                                float* __restrict__ Cc) {
  int idx = blockIdx.x * 256 + threadIdx.x;
  if (idx >= kMX * 128) return;
  int s = idx & 15, h = (idx >> 4) & 7, bt = idx >> 7;
  const bf16* xp = sx + (size_t)bt * 512 + h * 64;
  const float* wd = dtw + (h * 16 + s) * 64;
  const float* wb = Bw + (h * 16 + s) * 64;
  const float* wc = Cw + (h * 16 + s) * 64;
  float dd = 0.f, db = 0.f, dc = 0.f;
#pragma unroll 8
  for (int d = 0; d < 64; ++d) {
    float xv = __bfloat162float(xp[d]);
    dd += xv * wd[d];
    db += xv * wb[d];
    dc += xv * wc[d];
  }
  float raw = dd + dtb[h * 16 + s];
  float sp = fmaxf(raw, 0.f) + log1pf(expf(-fabsf(raw)));
  float dt = fminf(sp, 1.f);
  float A = fminf(-expf(logA[h * 16 + s]), 10.f);
  float lav = fminf(fmaxf(dt * A, -0.5f), 0.f);
  la[idx] = lav;
  u[idx] = db * dt;
  Cc[idx] = dc;
}

__global__ __launch_bounds__(256) void ssm_scan1(const float* __restrict__ la, const float* __restrict__ u,
                                                 bf16* __restrict__ hloc, bf16* __restrict__ Pb,
                                                 float* __restrict__ chH, float* __restrict__ chP) {
  int id = blockIdx.x * 256 + threadIdx.x;
  if (id >= 8192) return;
  int hs = id & 127, c = (id >> 7) & 31, b = id >> 12;
  float hv = 0.f, cum = 0.f;
  size_t base = ((size_t)b * kT) * 128 + hs;
  for (int i = 0; i < 64; ++i) {
    size_t ix = base + (size_t)(c * 64 + i) * 128;
    float lav = la[ix], uv = u[ix];
    cum += lav;
    hv = expf(lav) * hv + uv;
    hloc[ix] = __float2bfloat16(hv);
    Pb[ix] = __float2bfloat16(expf(fmaxf(cum, -30.f)));
  }
  chH[id] = hv;
  chP[id] = expf(fmaxf(cum, -30.f));
}

__global__ __launch_bounds__(256) void ssm_scan2(const float* __restrict__ chH,
                                                 const float* __restrict__ chP,
                                                 float* __restrict__ h0) {
  int id = threadIdx.x;
  int b = id >> 7, hs = id & 127;
  float h0v = 0.f;
  for (int c = 0; c < 32; ++c) {
    int ci = b * 4096 + c * 128 + hs;
    h0[ci] = h0v;
    h0v = chH[ci] + chP[ci] * h0v;
  }
}

__global__ __launch_bounds__(256) void ssm_out(const bf16* __restrict__ hloc, const bf16* __restrict__ Pb,
                                               const float* __restrict__ h0, const float* __restrict__ Cc,
                                               const bf16* __restrict__ sx, const float* __restrict__ Ow,
                                               const float* __restrict__ ssm_scale, bf16* __restrict__ Y) {
  int id = blockIdx.x * 256 + threadIdx.x;
  if (id >= kMX * 8) return;
  int h = id & 7, t = (id >> 3) & 2047, b = id >> 14;
  size_t ix0 = ((size_t)(b * kT + t)) * 128 + h * 16;
  int h0b = b * 4096 + (t >> 6) * 128 + h * 16;
  float hv[16], y = 0.f;
#pragma unroll
  for (int s = 0; s < 16; ++s) {
    float v = __bfloat162float(hloc[ix0 + s]) + __bfloat162float(Pb[ix0 + s]) * h0[h0b + s];
    hv[s] = v;
    y += Cc[ix0 + s] * v;
  }
  float x0 = __bfloat162float(sx[((size_t)(b * kT + t)) * 512 + h * 64]);
  float scl = ssm_scale[0];
  const float* ow = Ow + (size_t)h * 64 * 16;
  bf16* dst = Y + ((size_t)(b * kT + t)) * kDIM + 512 + h * 64;
  for (int d = 0; d < 64; ++d) {
    float acc = y * x0;
    const float* owr = ow + d * 16;
#pragma unroll
    for (int s = 0; s < 16; ++s) acc += hv[s] * owr[s];
    dst[d] = __float2bfloat16(acc * scl);
  }
}

// ---------------- host ----------------
extern "C" void kernel_launch(void* const* d_in, const int* in_sizes, int n_in,
                              void* d_out, int out_size, void* d_ws, size_t ws_size,
                              hipStream_t stream) {
  (void)in_sizes; (void)n_in; (void)out_size; (void)ws_size;
  const float* x        = (const float*)d_in[0];
  const float* meta     = (const float*)d_in[1];
  const float* c_q_w    = (const float*)d_in[2];
  const float* c_k_w    = (const float*)d_in[3];
  const float* c_v_w    = (const float*)d_in[4];
  const float* q_gain   = (const float*)d_in[5];
  const float* ssm_in_w = (const float*)d_in[6];
  const float* proj_w   = (const float*)d_in[7];
  const float* attn_sc  = (const float*)d_in[8];
  const float* ssm_sc   = (const float*)d_in[9];
  const float* ssm_logA = (const float*)d_in[10];
  const float* ssm_Bw   = (const float*)d_in[11];
  const float* ssm_Cw   = (const float*)d_in[12];
  const float* ssm_dtw  = (const float*)d_in[13];
  const float* ssm_dtb  = (const float*)d_in[14];
  const float* ssm_Ow   = (const float*)d_in[15];

  char* w = (char*)d_ws;
  bf16*  XE = (bf16*)(w + oXE);
  bf16*  QB = (bf16*)(w + oQB);
  bf16*  KB = (bf16*)(w + oKB);
  bf16*  VB = (bf16*)(w + oVB);
  bf16*  SX = (bf16*)(w + oSX);
  bf16*  YB = (bf16*)(w + oYB);
  bf16*  QP = (bf16*)(w + oQP);
  bf16*  KP = (bf16*)(w + oKP);
  bf16*  VT = (bf16*)(w + oVT);
  float* LA = (float*)(w + oLA);
  float* UU = (float*)(w + oUU);
  float* CC = (float*)(w + oCC);
  bf16*  HL = (bf16*)(w + oHL);
  bf16*  PB = (bf16*)(w + oPB);
  float* CH = (float*)(w + oCH);
  float* CP = (float*)(w + oCP);
  float* H0 = (float*)(w + oH0);

  build_xext<<<(kMPAD * 128 + 255) / 256, 256, 0, stream>>>(x, meta, XE);

  gemm_bt<false, false><<<dim3(8, kMPAD / 64), 256, 0, stream>>>(XE, c_q_w, QB, 512, 1024);
  gemm_bt<false, false><<<dim3(4, kMPAD / 64), 256, 0, stream>>>(XE, c_k_w, KB, 256, 1024);
  gemm_bt<false, false><<<dim3(4, kMPAD / 64), 256, 0, stream>>>(XE, c_v_w, VB, 256, 1024);
  gemm_bt<true,  false><<<dim3(8, kMX / 64), 256, 0, stream>>>(x, ssm_in_w, SX, 512, 1024);

  norm_rope_pack<<<(kB * kTP * 12) / 4, 256, 0, stream>>>(QB, KB, q_gain, QP, KP);
  vrepack<<<dim3(kQT, 4, kB), 256, 0, stream>>>(VB, VT);

  attn_mfma<<<dim3(kQT, 8, kB), 256, 0, stream>>>(QP, KP, VT, attn_sc, YB);

  ssm_prep<<<(kMX * 128 + 255) / 256, 256, 0, stream>>>(SX, ssm_dtw, ssm_dtb, ssm_Bw, ssm_Cw,
                                                        ssm_logA, LA, UU, CC);
  ssm_scan1<<<32, 256, 0, stream>>>(LA, UU, HL, PB, CH, CP);
  ssm_scan2<<<1, 256, 0, stream>>>(CH, CP, H0);
  ssm_out<<<(kMX * 8 + 255) / 256, 256, 0, stream>>>(HL, PB, H0, CC, SX, ssm_Ow, ssm_sc, YB);

  gemm_bt<false, true><<<dim3(16, kMX / 64), 256, 0, stream>>>(YB, proj_w, d_out, 1024, 1024);
}

// Round 5
// 326.743 us; speedup vs baseline: 2.4090x; 1.2113x over previous
//
#include <hip/hip_runtime.h>
#include <hip/hip_bf16.h>
#include <math.h>

typedef __hip_bfloat16 bf16;
typedef __attribute__((ext_vector_type(8))) short short8;   // 8 bf16 = 4 VGPRs (MFMA A/B frag)
typedef __attribute__((ext_vector_type(4))) float f32x4;    // MFMA C/D frag

static constexpr int kB = 2;
static constexpr int kT = 2048;
static constexpr int kDIM = 1024;
static constexpr int kNMETA = 4;
static constexpr int kTEXT = kT + kNMETA;   // 2052
static constexpr int kMEXT = kB * kTEXT;    // 4104
static constexpr int kMPAD = 4160;          // 65*64, zero-padded rows for guard-free GEMM
static constexpr int kMX = kB * kT;         // 4096
static constexpr int kQT = 33;              // ceil(2052/64)
static constexpr int kTP = 2112;            // 33*64 padded sequence length

// ---------- workspace layout (bytes), high-water ~29.9 MB (proven in R4) ----------
static constexpr size_t oXE = 0;                                  // x_ext bf16 [4160][1024]
static constexpr size_t oYB = 0;                                  // aliases XE (dead after GEMMs)
static constexpr size_t oQB = 8519680;                            // Q bf16 [4160][512]
static constexpr size_t oKB = oQB + (size_t)kMPAD * 512 * 2;      // K bf16 [4160][256]
static constexpr size_t oVB = oKB + (size_t)kMPAD * 256 * 2;      // V bf16 [4160][256]
// SSM intermediates alias QB/KB/VB after attention:
static constexpr size_t oLA = oQB;                                // la f32 [4096][128]
static constexpr size_t oUU = oLA + (size_t)kMX * 128 * 4;
static constexpr size_t oCC = oUU + (size_t)kMX * 128 * 4;
static constexpr size_t oHL = oCC + (size_t)kMX * 128 * 4;        // hloc bf16
static constexpr size_t oPB = oHL + (size_t)kMX * 128 * 2;        // P    bf16
static constexpr size_t oCH = oPB + (size_t)kMX * 128 * 2;        // chunk h  f32 [8192]
static constexpr size_t oCP = oCH + 8192 * 4;
static constexpr size_t oH0 = oCP + 8192 * 4;
static constexpr size_t oSX = oVB + (size_t)kMPAD * 256 * 2;      // ssm x bf16 [4096][512]
// packed attention operands (QP region also hosts bf16 weights early: dead by norm_rope_pack):
static constexpr size_t oQP = oSX + (size_t)kMX * 512 * 2;        // Qp bf16 [b][8][2112][64]
static constexpr size_t oKP = oQP + (size_t)kB * 8 * kTP * 64 * 2;// Kp bf16 [b][4][2112][64]
static constexpr size_t oVT = oKP + (size_t)kB * 4 * kTP * 64 * 2;// Vt bf16 [b][4][64][2112]
static constexpr size_t oWQ = oQP;                                // WQKV bf16 [1024][1024] (early)
static constexpr size_t oWS = oQP + 2097152;                      // WSX  bf16 [512][1024]  (early)

__device__ __forceinline__ float bf2f(unsigned short u) {
  return __uint_as_float(((unsigned int)u) << 16);
}

// pack 8 f32 -> 8 bf16 (RNE) in a uint4
__device__ __forceinline__ uint4 pack8(float4 a, float4 b) {
  union { bf16 h[8]; uint4 v; } u;
  u.h[0] = __float2bfloat16(a.x); u.h[1] = __float2bfloat16(a.y);
  u.h[2] = __float2bfloat16(a.z); u.h[3] = __float2bfloat16(a.w);
  u.h[4] = __float2bfloat16(b.x); u.h[5] = __float2bfloat16(b.y);
  u.h[6] = __float2bfloat16(b.z); u.h[7] = __float2bfloat16(b.w);
  return u.v;
}

// ---------------- weight concat+convert: f32 -> bf16 ----------------
__global__ __launch_bounds__(256) void wconv(const float* __restrict__ cq, const float* __restrict__ ck,
                                             const float* __restrict__ cv, const float* __restrict__ sw,
                                             bf16* __restrict__ wqkv, bf16* __restrict__ wsx) {
  int i = blockIdx.x * 256 + threadIdx.x;     // 8-elem groups; total 1536*128
  if (i >= 1536 * 128) return;
  int row = i >> 7, v = i & 127;
  const float* src; bf16* dst;
  if (row < 1024) {
    dst = wqkv + (size_t)row * 1024;
    src = (row < 512) ? cq + (size_t)row * 1024
        : (row < 768) ? ck + (size_t)(row - 512) * 1024
                      : cv + (size_t)(row - 768) * 1024;
  } else {
    dst = wsx + (size_t)(row - 1024) * 1024;
    src = sw + (size_t)(row - 1024) * 1024;
  }
  float4 a0 = ((const float4*)src)[v * 2], a1 = ((const float4*)src)[v * 2 + 1];
  ((uint4*)dst)[v] = pack8(a0, a1);
}

// ---------------- build x_ext = [meta ; x] (f32 -> bf16), zero-pad rows to 4160 -------------
__global__ __launch_bounds__(256) void build_xext(const float* __restrict__ x,
                                                  const float* __restrict__ meta,
                                                  bf16* __restrict__ xe) {
  int i = blockIdx.x * 256 + threadIdx.x;
  int row = i >> 7, v = i & 127;
  if (row >= kMPAD) return;
  uint4 val = {0u, 0u, 0u, 0u};
  if (row < kMEXT) {
    int b = row / kTEXT, te = row - b * kTEXT;
    const float* src = (te < kNMETA) ? (meta + (size_t)te * kDIM)
                                     : (x + ((size_t)b * kT + (te - kNMETA)) * kDIM);
    float4 a0 = ((const float4*)src)[v * 2];
    float4 a1 = ((const float4*)src)[v * 2 + 1];
    val = pack8(a0, a1);
  }
  ((uint4*)(xe + (size_t)row * kDIM))[v] = val;
}

// ================= shared 64x64 bf16 GEMM body (K=1024) =================
// MODE 0: QKV fused (A=XE rows direct; split epilogue Q/K/V)
// MODE 1: SX (A=XE with row map b*2052+4+t; out bf16 SX stride 512)
// MODE 2: proj (A=YB rows direct; W f32 packed in-loop; out f32 stride 1024)
template <int MODE>
__global__ __launch_bounds__(256) void gemm64(const bf16* __restrict__ A,
                                              const void* __restrict__ Wv,
                                              void* __restrict__ O0, void* __restrict__ O1,
                                              void* __restrict__ O2) {
  __shared__ short As[64][40];
  __shared__ short Bs[64][40];
  const int tid = threadIdx.x;
  const int wave = tid >> 6, lane = tid & 63;
  const int wr = wave >> 1, wc = wave & 1;
  const int quad = lane >> 4, l16 = lane & 15;
  const int bm = blockIdx.y * 64, bn = blockIdx.x * 64;
  const int srow = tid >> 2, scol = (tid & 3) * 8;
  int arow = bm + srow;
  if constexpr (MODE == 1) { int r = bm + srow; arow = (r >> 11) * kTEXT + kNMETA + (r & 2047); }
  f32x4 acc[2][2] = {};
  const bf16* ap = A + (size_t)arow * 1024 + scol;
  const bf16* wb = (MODE == 2) ? nullptr : ((const bf16*)Wv + (size_t)(bn + srow) * 1024 + scol);
  const float* wf = (MODE == 2) ? ((const float*)Wv + (size_t)(bn + srow) * 1024 + scol) : nullptr;
  for (int k0 = 0; k0 < 1024; k0 += 32) {
    uint4 av = *(const uint4*)ap; ap += 32;
    uint4 bv;
    if constexpr (MODE == 2) {
      bv = pack8(((const float4*)wf)[0], ((const float4*)wf)[1]);
      wf += 32;
    } else {
      bv = *(const uint4*)wb; wb += 32;
    }
    __syncthreads();
    *(uint4*)&As[srow][scol] = av;
    *(uint4*)&Bs[srow][scol] = bv;
    __syncthreads();
    short8 af[2], bfr[2];
#pragma unroll
    for (int i = 0; i < 2; ++i) af[i] = *(const short8*)&As[wr * 32 + i * 16 + l16][quad * 8];
#pragma unroll
    for (int j = 0; j < 2; ++j) bfr[j] = *(const short8*)&Bs[wc * 32 + j * 16 + l16][quad * 8];
#pragma unroll
    for (int i = 0; i < 2; ++i)
#pragma unroll
      for (int j = 0; j < 2; ++j)
        acc[i][j] = __builtin_amdgcn_mfma_f32_16x16x32_bf16(af[i], bfr[j], acc[i][j], 0, 0, 0);
  }
  // epilogue
  bf16* outb = nullptr; float* outf = nullptr;
  int colbase = bn, stride = 0;
  if constexpr (MODE == 0) {
    if (bn < 512)      { outb = (bf16*)O0; colbase = bn;       stride = 512; }
    else if (bn < 768) { outb = (bf16*)O1; colbase = bn - 512; stride = 256; }
    else               { outb = (bf16*)O2; colbase = bn - 768; stride = 256; }
  } else if constexpr (MODE == 1) {
    outb = (bf16*)O0; stride = 512;
  } else {
    outf = (float*)O0; stride = 1024;
  }
#pragma unroll
  for (int i = 0; i < 2; ++i)
#pragma unroll
    for (int j = 0; j < 2; ++j) {
      int row0 = bm + wr * 32 + i * 16 + quad * 4;
      int col = colbase + wc * 32 + j * 16 + l16;
#pragma unroll
      for (int r = 0; r < 4; ++r) {
        size_t off = (size_t)(row0 + r) * stride + col;
        if constexpr (MODE == 2) outf[off] = acc[i][j][r];
        else                     outb[off] = __float2bfloat16(acc[i][j][r]);
      }
    }
}

// ------- RMSnorm + RoPE (+q_gain, +1/sqrt(D)) -> packed Qp[b][8][2112][64], Kp[b][4][2112][64]
__global__ __launch_bounds__(256) void norm_rope_pack(const bf16* __restrict__ QB,
                                                      const bf16* __restrict__ KB,
                                                      const float* __restrict__ q_gain,
                                                      bf16* __restrict__ Qp, bf16* __restrict__ Kp) {
  int job = blockIdx.x * 4 + (threadIdx.x >> 6);
  if (job >= kB * kTP * 12) return;
  int lane = threadIdx.x & 63;
  int slot = job % 12, rowp = job / 12;
  int b = rowp / kTP, te = rowp % kTP;
  bf16* dst = (slot < 8) ? Qp + (((size_t)(b * 8 + slot)) * kTP + te) * 64 + lane
                         : Kp + (((size_t)(b * 4 + slot - 8)) * kTP + te) * 64 + lane;
  if (te >= kTEXT) { *dst = __float2bfloat16(0.f); return; }
  const bf16* src = (slot < 8) ? QB + ((size_t)(b * kTEXT + te)) * 512 + slot * 64 + lane
                               : KB + ((size_t)(b * kTEXT + te)) * 256 + (slot - 8) * 64 + lane;
  float v = __bfloat162float(*src);
  float ss = v * v;
#pragma unroll
  for (int o = 32; o > 0; o >>= 1) ss += __shfl_xor(ss, o, 64);
  float vn = v * (1.f / sqrtf(ss * (1.f / 64.f) + 1e-6f));
  float p = __shfl_xor(vn, 32, 64);
  float ang = (float)te * exp2f(-13.287712379549449f * (float)(lane & 31) * (1.f / 32.f));
  float c = cosf(ang), s = sinf(ang);
  float outv = (lane < 32) ? (vn * c - p * s) : (p * s + vn * c);
  float gain = (slot < 8) ? q_gain[slot] * 0.125f : 1.f;
  *dst = __float2bfloat16(outv * gain);
}

// ------- V transpose: VB[row][256] -> Vt[b][kvh][64][2112] (zero pads), LDS-tiled -------
__global__ __launch_bounds__(256) void vrepack(const bf16* __restrict__ VB, bf16* __restrict__ Vt) {
  __shared__ short Ts[64][66];
  const int tt = blockIdx.x, kvh = blockIdx.y, b = blockIdx.z;
  const int tid = threadIdx.x;
#pragma unroll
  for (int r = 0; r < 2; ++r) {
    int e = r * 256 + tid, row = e >> 3, c8 = e & 7;
    int te = tt * 64 + row;
    uint4 val = {0u, 0u, 0u, 0u};
    if (te < kTEXT) val = *(const uint4*)(VB + ((size_t)(b * kTEXT + te)) * 256 + kvh * 64 + c8 * 8);
    union { uint4 u; short s[8]; } w; w.u = val;
#pragma unroll
    for (int i = 0; i < 8; ++i) Ts[row][c8 * 8 + i] = w.s[i];
  }
  __syncthreads();
#pragma unroll
  for (int r = 0; r < 2; ++r) {
    int e = r * 256 + tid, d = e >> 3, c8 = e & 7;
    union { uint4 u; short s[8]; } w;
#pragma unroll
    for (int i = 0; i < 8; ++i) w.s[i] = Ts[c8 * 8 + i][d];
    *(uint4*)(Vt + (((size_t)(b * 4 + kvh)) * 64 + d) * kTP + tt * 64 + c8 * 8) = w.u;
  }
}

// ---------------- MFMA causal flash attention v2 ----------------
// Fixed-max softmax (|score|<=8 guaranteed by rms_norm), S^T = K*Q^T so P spills as b64,
// row-sum l via ones-MFMA. 64 q-rows/block (4 waves x 16), 64-key tiles.
__global__ __launch_bounds__(256) void attn_mfma(const bf16* __restrict__ Qp,
                                                 const bf16* __restrict__ Kp,
                                                 const bf16* __restrict__ Vt,
                                                 const float* __restrict__ attn_scale,
                                                 bf16* __restrict__ Y) {
  __shared__ short Ks[64][72];        // K tile [key][d]
  __shared__ short Vs[64][72];        // V^T tile [d][key]
  __shared__ short Ps[4][16][72];     // per-wave P [q][key]
  const int qt = (kQT - 1) - blockIdx.x;   // longest first
  const int h = blockIdx.y, b = blockIdx.z;
  const int kvh = h >> 1;
  const int tid = threadIdx.x, wave = tid >> 6, lane = tid & 63;
  const int quad = lane >> 4, l16 = lane & 15;

  // Q B-frags in registers (scale+gain pre-folded); B-frag = [n=l16][k=quad*8+j]
  short8 qf[2];
  {
    const bf16* qrow = Qp + (((size_t)(b * 8 + h)) * kTP + qt * 64 + wave * 16 + l16) * 64 + quad * 8;
    qf[0] = *(const short8*)(qrow);
    qf[1] = *(const short8*)(qrow + 32);
  }
  short8 ones;
#pragma unroll
  for (int i = 0; i < 8; ++i) ones[i] = (short)0x3F80;   // bf16 1.0

  const bf16* kbase = Kp + ((size_t)(b * 4 + kvh)) * kTP * 64;
  const bf16* vbase = Vt + ((size_t)(b * 4 + kvh)) * 64 * kTP;

  f32x4 O[4] = {};
  f32x4 lacc = {};
  const int q_abs = qt * 64 + wave * 16 + l16;   // q owned by this lane in S^T tiles

  for (int kt = 0; kt <= qt; ++kt) {
    __syncthreads();   // prior-iter LDS reads done
#pragma unroll
    for (int r = 0; r < 2; ++r) {
      int e = r * 256 + tid, row = e >> 3, c8 = e & 7;
      uint4 kv = *(const uint4*)(kbase + ((size_t)(kt * 64 + row)) * 64 + c8 * 8);
      *(uint4*)&Ks[row][c8 * 8] = kv;
      uint4 vv = *(const uint4*)(vbase + (size_t)row * kTP + kt * 64 + c8 * 8);
      *(uint4*)&Vs[row][c8 * 8] = vv;
    }
    __syncthreads();

    // ---- S^T = K * Q^T : rows = keys, cols = q ----
    f32x4 st[4] = {};
#pragma unroll
    for (int nb = 0; nb < 4; ++nb) {
      short8 ak0 = *(const short8*)&Ks[nb * 16 + l16][quad * 8];
      st[nb] = __builtin_amdgcn_mfma_f32_16x16x32_bf16(ak0, qf[0], st[nb], 0, 0, 0);
      short8 ak1 = *(const short8*)&Ks[nb * 16 + l16][32 + quad * 8];
      st[nb] = __builtin_amdgcn_mfma_f32_16x16x32_bf16(ak1, qf[1], st[nb], 0, 0, 0);
    }
    // ---- causal mask on diagonal tile: lane holds keys kt*64+nb*16+quad*4+rg, q=q_abs ----
    if (kt == qt) {
      int key0 = kt * 64 + quad * 4;
#pragma unroll
      for (int nb = 0; nb < 4; ++nb)
#pragma unroll
        for (int rg = 0; rg < 4; ++rg)
          if (key0 + nb * 16 + rg > q_abs) st[nb][rg] = -1e30f;
    }
    // ---- P = exp(score) (fixed max 0), spill as b64 per nb ----
#pragma unroll
    for (int nb = 0; nb < 4; ++nb) {
      union { unsigned long long q; bf16 hh[4]; } pw;
#pragma unroll
      for (int rg = 0; rg < 4; ++rg) pw.hh[rg] = __float2bfloat16(__expf(st[nb][rg]));
      *(unsigned long long*)&Ps[wave][l16][nb * 16 + quad * 4] = pw.q;
    }
    // ---- P A-frags (wave-private LDS; in-wave lgkmcnt ordering suffices) ----
    short8 pf0 = *(const short8*)&Ps[wave][l16][quad * 8];
    short8 pf1 = *(const short8*)&Ps[wave][l16][32 + quad * 8];
    // ---- l += P @ ones ----
    lacc = __builtin_amdgcn_mfma_f32_16x16x32_bf16(pf0, ones, lacc, 0, 0, 0);
    lacc = __builtin_amdgcn_mfma_f32_16x16x32_bf16(pf1, ones, lacc, 0, 0, 0);
    // ---- O += P @ V : B-frag = Vs[d][key] ----
#pragma unroll
    for (int db = 0; db < 4; ++db) {
      short8 bv0 = *(const short8*)&Vs[db * 16 + l16][quad * 8];
      O[db] = __builtin_amdgcn_mfma_f32_16x16x32_bf16(pf0, bv0, O[db], 0, 0, 0);
      short8 bv1 = *(const short8*)&Vs[db * 16 + l16][32 + quad * 8];
      O[db] = __builtin_amdgcn_mfma_f32_16x16x32_bf16(pf1, bv1, O[db], 0, 0, 0);
    }
  }
  // ---- epilogue: O row = q = quad*4+rg (+wave*16), col = d = db*16+l16 ----
  float asc = attn_scale[0];
#pragma unroll
  for (int rg = 0; rg < 4; ++rg) {
    int te_q = qt * 64 + wave * 16 + quad * 4 + rg;
    if (te_q < kNMETA || te_q >= kTEXT) continue;
    float so = asc / fmaxf(lacc[rg], 1e-30f);
    bf16* dst = Y + ((size_t)(b * kT + te_q - kNMETA)) * kDIM + h * 64 + l16;
#pragma unroll
    for (int db = 0; db < 4; ++db) dst[db * 16] = __float2bfloat16(O[db][rg] * so);
  }
}

// ---------------- SSM: dt / la / u / Cc per (b,t,h,s) ----------------
__global__ __launch_bounds__(256) void ssm_prep(const bf16* __restrict__ sx,
                                                const float* __restrict__ dtw, const float* __restrict__ dtb,
                                                const float* __restrict__ Bw, const float* __restrict__ Cw,
                                                const float* __restrict__ logA,
                                                float* __restrict__ la, float* __restrict__ u,
                                                float* __restrict__ Cc) {
  int idx = blockIdx.x * 256 + threadIdx.x;
  if (idx >= kMX * 128) return;
  int s = idx & 15, h = (idx >> 4) & 7, bt = idx >> 7;
  const bf16* xp = sx + (size_t)bt * 512 + h * 64;
  const float* wd = dtw + (h * 16 + s) * 64;
  const float* wb = Bw + (h * 16 + s) * 64;
  const float* wc = Cw + (h * 16 + s) * 64;
  float dd = 0.f, db = 0.f, dc = 0.f;
#pragma unroll 8
  for (int d = 0; d < 64; ++d) {
    float xv = __bfloat162float(xp[d]);
    dd += xv * wd[d];
    db += xv * wb[d];
    dc += xv * wc[d];
  }
  float raw = dd + dtb[h * 16 + s];
  float sp = fmaxf(raw, 0.f) + log1pf(expf(-fabsf(raw)));
  float dt = fminf(sp, 1.f);
  float A = fminf(-expf(logA[h * 16 + s]), 10.f);
  float lav = fminf(fmaxf(dt * A, -0.5f), 0.f);
  la[idx] = lav;
  u[idx] = db * dt;
  Cc[idx] = dc;
}

__global__ __launch_bounds__(256) void ssm_scan1(const float* __restrict__ la, const float* __restrict__ u,
                                                 bf16* __restrict__ hloc, bf16* __restrict__ Pb,
                                                 float* __restrict__ chH, float* __restrict__ chP) {
  int id = blockIdx.x * 256 + threadIdx.x;
  if (id >= 8192) return;
  int hs = id & 127, c = (id >> 7) & 31, b = id >> 12;
  float hv = 0.f, cum = 0.f;
  size_t base = ((size_t)b * kT) * 128 + hs;
  for (int i = 0; i < 64; ++i) {
    size_t ix = base + (size_t)(c * 64 + i) * 128;
    float lav = la[ix], uv = u[ix];
    cum += lav;
    hv = expf(lav) * hv + uv;
    hloc[ix] = __float2bfloat16(hv);
    Pb[ix] = __float2bfloat16(expf(fmaxf(cum, -30.f)));
  }
  chH[id] = hv;
  chP[id] = expf(fmaxf(cum, -30.f));
}

__global__ __launch_bounds__(256) void ssm_scan2(const float* __restrict__ chH,
                                                 const float* __restrict__ chP,
                                                 float* __restrict__ h0) {
  int id = threadIdx.x;
  int b = id >> 7, hs = id & 127;
  float h0v = 0.f;
  for (int c = 0; c < 32; ++c) {
    int ci = b * 4096 + c * 128 + hs;
    h0[ci] = h0v;
    h0v = chH[ci] + chP[ci] * h0v;
  }
}

__global__ __launch_bounds__(256) void ssm_out(const bf16* __restrict__ hloc, const bf16* __restrict__ Pb,
                                               const float* __restrict__ h0, const float* __restrict__ Cc,
                                               const bf16* __restrict__ sx, const float* __restrict__ Ow,
                                               const float* __restrict__ ssm_scale, bf16* __restrict__ Y) {
  int id = blockIdx.x * 256 + threadIdx.x;
  if (id >= kMX * 8) return;
  int h = id & 7, t = (id >> 3) & 2047, b = id >> 14;
  size_t ix0 = ((size_t)(b * kT + t)) * 128 + h * 16;
  int h0b = b * 4096 + (t >> 6) * 128 + h * 16;
  float hv[16], y = 0.f;
#pragma unroll
  for (int s = 0; s < 16; ++s) {
    float v = __bfloat162float(hloc[ix0 + s]) + __bfloat162float(Pb[ix0 + s]) * h0[h0b + s];
    hv[s] = v;
    y += Cc[ix0 + s] * v;
  }
  float x0 = __bfloat162float(sx[((size_t)(b * kT + t)) * 512 + h * 64]);
  float scl = ssm_scale[0];
  const float* ow = Ow + (size_t)h * 64 * 16;
  bf16* dst = Y + ((size_t)(b * kT + t)) * kDIM + 512 + h * 64;
  for (int d = 0; d < 64; ++d) {
    float acc = y * x0;
    const float* owr = ow + d * 16;
#pragma unroll
    for (int s = 0; s < 16; ++s) acc += hv[s] * owr[s];
    dst[d] = __float2bfloat16(acc * scl);
  }
}

// ---------------- host ----------------
extern "C" void kernel_launch(void* const* d_in, const int* in_sizes, int n_in,
                              void* d_out, int out_size, void* d_ws, size_t ws_size,
                              hipStream_t stream) {
  (void)in_sizes; (void)n_in; (void)out_size; (void)ws_size;
  const float* x        = (const float*)d_in[0];
  const float* meta     = (const float*)d_in[1];
  const float* c_q_w    = (const float*)d_in[2];
  const float* c_k_w    = (const float*)d_in[3];
  const float* c_v_w    = (const float*)d_in[4];
  const float* q_gain   = (const float*)d_in[5];
  const float* ssm_in_w = (const float*)d_in[6];
  const float* proj_w   = (const float*)d_in[7];
  const float* attn_sc  = (const float*)d_in[8];
  const float* ssm_sc   = (const float*)d_in[9];
  const float* ssm_logA = (const float*)d_in[10];
  const float* ssm_Bw   = (const float*)d_in[11];
  const float* ssm_Cw   = (const float*)d_in[12];
  const float* ssm_dtw  = (const float*)d_in[13];
  const float* ssm_dtb  = (const float*)d_in[14];
  const float* ssm_Ow   = (const float*)d_in[15];

  char* w = (char*)d_ws;
  bf16*  XE = (bf16*)(w + oXE);
  bf16*  QB = (bf16*)(w + oQB);
  bf16*  KB = (bf16*)(w + oKB);
  bf16*  VB = (bf16*)(w + oVB);
  bf16*  SX = (bf16*)(w + oSX);
  bf16*  YB = (bf16*)(w + oYB);
  bf16*  QP = (bf16*)(w + oQP);
  bf16*  KP = (bf16*)(w + oKP);
  bf16*  VT = (bf16*)(w + oVT);
  bf16*  WQ = (bf16*)(w + oWQ);
  bf16*  WS = (bf16*)(w + oWS);
  float* LA = (float*)(w + oLA);
  float* UU = (float*)(w + oUU);
  float* CC = (float*)(w + oCC);
  bf16*  HL = (bf16*)(w + oHL);
  bf16*  PB = (bf16*)(w + oPB);
  float* CH = (float*)(w + oCH);
  float* CP = (float*)(w + oCP);
  float* H0 = (float*)(w + oH0);

  wconv<<<768, 256, 0, stream>>>(c_q_w, c_k_w, c_v_w, ssm_in_w, WQ, WS);
  build_xext<<<(kMPAD * 128 + 255) / 256, 256, 0, stream>>>(x, meta, XE);

  gemm64<0><<<dim3(16, kMPAD / 64), 256, 0, stream>>>(XE, WQ, QB, KB, VB);   // fused QKV
  gemm64<1><<<dim3(8, kMX / 64), 256, 0, stream>>>(XE, WS, SX, nullptr, nullptr);

  norm_rope_pack<<<(kB * kTP * 12) / 4, 256, 0, stream>>>(QB, KB, q_gain, QP, KP);
  vrepack<<<dim3(kQT, 4, kB), 256, 0, stream>>>(VB, VT);

  attn_mfma<<<dim3(kQT, 8, kB), 256, 0, stream>>>(QP, KP, VT, attn_sc, YB);

  ssm_prep<<<(kMX * 128 + 255) / 256, 256, 0, stream>>>(SX, ssm_dtw, ssm_dtb, ssm_Bw, ssm_Cw,
                                                        ssm_logA, LA, UU, CC);
  ssm_scan1<<<32, 256, 0, stream>>>(LA, UU, HL, PB, CH, CP);
  ssm_scan2<<<1, 256, 0, stream>>>(CH, CP, H0);
  ssm_out<<<(kMX * 8 + 255) / 256, 256, 0, stream>>>(HL, PB, H0, CC, SX, ssm_Ow, ssm_sc, YB);

  gemm64<2><<<dim3(16, kMX / 64), 256, 0, stream>>>(YB, proj_w, d_out, nullptr, nullptr);
}

// Round 6
// 280.423 us; speedup vs baseline: 2.8069x; 1.1652x over previous
//
#include <hip/hip_runtime.h>
#include <hip/hip_bf16.h>
#include <math.h>

typedef __hip_bfloat16 bf16;
typedef __attribute__((ext_vector_type(8))) short short8;   // 8 bf16 = 4 VGPRs (MFMA A/B frag)
typedef __attribute__((ext_vector_type(4))) float f32x4;    // MFMA C/D frag

static constexpr int kB = 2;
static constexpr int kT = 2048;
static constexpr int kDIM = 1024;
static constexpr int kNMETA = 4;
static constexpr int kTEXT = kT + kNMETA;   // 2052
static constexpr int kMEXT = kB * kTEXT;    // 4104
static constexpr int kMPAD = 4224;          // 33*128, zero-padded rows for guard-free 128-tile GEMM
static constexpr int kMX = kB * kT;         // 4096
static constexpr int kQT = 33;              // ceil(2052/64)
static constexpr int kTP = 2112;            // 33*64 padded sequence length

// ---------- workspace layout (bytes), high-water ~30.1 MB ----------
static constexpr size_t oXE = 0;                                  // x_ext bf16 [4224][1024]
static constexpr size_t oYB = 0;                                  // aliases XE (dead after GEMMs)
static constexpr size_t oQB = 8650752;                            // Q bf16 [4224][512]
static constexpr size_t oKB = oQB + (size_t)kMPAD * 512 * 2;      // K bf16 [4224][256]
static constexpr size_t oVB = oKB + (size_t)kMPAD * 256 * 2;      // V bf16 [4224][256]
// SSM intermediates alias QB/KB/VB after attention (8.49 MB <= 8.65 MB region):
static constexpr size_t oLA = oQB;                                // la f32 [4096][128]
static constexpr size_t oUU = oLA + (size_t)kMX * 128 * 4;
static constexpr size_t oCC = oUU + (size_t)kMX * 128 * 4;
static constexpr size_t oHL = oCC + (size_t)kMX * 128 * 4;        // hloc bf16
static constexpr size_t oPB = oHL + (size_t)kMX * 128 * 2;        // P    bf16
static constexpr size_t oCH = oPB + (size_t)kMX * 128 * 2;        // chunk h  f32 [8192]
static constexpr size_t oCP = oCH + 8192 * 4;
static constexpr size_t oH0 = oCP + 8192 * 4;
static constexpr size_t oSX = oVB + (size_t)kMPAD * 256 * 2;      // ssm x bf16 [4096][512]
// packed attention operands (QP region also hosts bf16 weights early & proj weights late):
static constexpr size_t oQP = oSX + (size_t)kMX * 512 * 2;        // Qp bf16 [b][8][2112][64]
static constexpr size_t oKP = oQP + (size_t)kB * 8 * kTP * 64 * 2;// Kp bf16 [b][4][2112][64]
static constexpr size_t oVT = oKP + (size_t)kB * 4 * kTP * 64 * 2;// Vt bf16 [b][4][64][2112]
static constexpr size_t oWQ = oQP;                                // WQKV bf16 [1024][1024] (early, dead before norm_rope_pack)
static constexpr size_t oWS = oQP + 2097152;                      // WSX  bf16 [512][1024]  (early)
static constexpr size_t oWP = oQP;                                // Wproj bf16 [1024][1024] (late: QP dead after attn)

#define GLD_LDS16(gp, lp)                                                          \
  __builtin_amdgcn_global_load_lds((const __attribute__((address_space(1))) void*)(gp), \
                                   (__attribute__((address_space(3))) void*)(lp), 16, 0, 0)

__device__ __forceinline__ float bf2f(unsigned short u) {
  return __uint_as_float(((unsigned int)u) << 16);
}

// pack 8 f32 -> 8 bf16 (RNE) in a uint4
__device__ __forceinline__ uint4 pack8(float4 a, float4 b) {
  union { bf16 h[8]; uint4 v; } u;
  u.h[0] = __float2bfloat16(a.x); u.h[1] = __float2bfloat16(a.y);
  u.h[2] = __float2bfloat16(a.z); u.h[3] = __float2bfloat16(a.w);
  u.h[4] = __float2bfloat16(b.x); u.h[5] = __float2bfloat16(b.y);
  u.h[6] = __float2bfloat16(b.z); u.h[7] = __float2bfloat16(b.w);
  return u.v;
}

// ---------------- weight concat+convert: f32 -> bf16 (QKV fused + SX) ----------------
__global__ __launch_bounds__(256) void wconv(const float* __restrict__ cq, const float* __restrict__ ck,
                                             const float* __restrict__ cv, const float* __restrict__ sw,
                                             bf16* __restrict__ wqkv, bf16* __restrict__ wsx) {
  int i = blockIdx.x * 256 + threadIdx.x;     // 8-elem groups; total 1536*128
  if (i >= 1536 * 128) return;
  int row = i >> 7, v = i & 127;
  const float* src; bf16* dst;
  if (row < 1024) {
    dst = wqkv + (size_t)row * 1024;
    src = (row < 512) ? cq + (size_t)row * 1024
        : (row < 768) ? ck + (size_t)(row - 512) * 1024
                      : cv + (size_t)(row - 768) * 1024;
  } else {
    dst = wsx + (size_t)(row - 1024) * 1024;
    src = sw + (size_t)(row - 1024) * 1024;
  }
  float4 a0 = ((const float4*)src)[v * 2], a1 = ((const float4*)src)[v * 2 + 1];
  ((uint4*)dst)[v] = pack8(a0, a1);
}

// ---------------- generic f32 -> bf16 row convert (proj weights, late) ----------------
__global__ __launch_bounds__(256) void wcvt(const float* __restrict__ src, bf16* __restrict__ dst, int n8) {
  int i = blockIdx.x * 256 + threadIdx.x;
  if (i >= n8) return;
  float4 a0 = ((const float4*)src)[i * 2], a1 = ((const float4*)src)[i * 2 + 1];
  ((uint4*)dst)[i] = pack8(a0, a1);
}

// ---------------- build x_ext = [meta ; x] (f32 -> bf16), zero-pad rows to 4224 -------------
__global__ __launch_bounds__(256) void build_xext(const float* __restrict__ x,
                                                  const float* __restrict__ meta,
                                                  bf16* __restrict__ xe) {
  int i = blockIdx.x * 256 + threadIdx.x;
  int row = i >> 7, v = i & 127;
  if (row >= kMPAD) return;
  uint4 val = {0u, 0u, 0u, 0u};
  if (row < kMEXT) {
    int b = row / kTEXT, te = row - b * kTEXT;
    const float* src = (te < kNMETA) ? (meta + (size_t)te * kDIM)
                                     : (x + ((size_t)b * kT + (te - kNMETA)) * kDIM);
    float4 a0 = ((const float4*)src)[v * 2];
    float4 a1 = ((const float4*)src)[v * 2 + 1];
    val = pack8(a0, a1);
  }
  ((uint4*)(xe + (size_t)row * kDIM))[v] = val;
}

// ================= 128x128-tile bf16 GEMM, m97 structure (K=1024, BK=32) =================
// global_load_lds width-16 staging; LDS [128 rows][32 bf16] = 64B rows, linear in tid*16.
// MODE 0: QKV fused (N=1024; epilogue splits Q/K/V). MODE 1: SX (N=512, input-row remap).
// MODE 2: proj (N=1024, f32 out).
template <int MODE>
__global__ __launch_bounds__(256) void gemm128(const bf16* __restrict__ A,
                                               const bf16* __restrict__ W,
                                               void* __restrict__ O0, void* __restrict__ O1,
                                               void* __restrict__ O2) {
  __shared__ short As[128 * 32];
  __shared__ short Bs[128 * 32];
  const int tid = threadIdx.x;
  const int wave = tid >> 6, lane = tid & 63;
  const int wr = wave >> 1, wc = wave & 1;
  const int quad = lane >> 4, l16 = lane & 15;
  const int bm = blockIdx.y * 128, bn = blockIdx.x * 128;
  const int srow = tid >> 2, scol = (tid & 3) * 8;   // staging: row tid>>2, 8-elem col group
  int arow0 = bm + srow, arow1 = bm + 64 + srow;
  if constexpr (MODE == 1) {
    int r0 = arow0; arow0 = (r0 >> 11) * kTEXT + kNMETA + (r0 & 2047);
    int r1 = arow1; arow1 = (r1 >> 11) * kTEXT + kNMETA + (r1 & 2047);
  }
  const bf16* ag0 = A + (size_t)arow0 * 1024 + scol;
  const bf16* ag1 = A + (size_t)arow1 * 1024 + scol;
  const bf16* bg0 = W + (size_t)(bn + srow) * 1024 + scol;
  const bf16* bg1 = W + (size_t)(bn + 64 + srow) * 1024 + scol;
  char* asb = (char*)As + wave * 1024;   // wave-uniform LDS base; lane*16 placement implicit
  char* bsb = (char*)Bs + wave * 1024;
  f32x4 acc[4][4] = {};
  for (int k0 = 0; k0 < 1024; k0 += 32) {
    __syncthreads();                     // previous iter's ds_reads done
    GLD_LDS16(ag0, asb);
    GLD_LDS16(ag1, asb + 4096);
    GLD_LDS16(bg0, bsb);
    GLD_LDS16(bg1, bsb + 4096);
    ag0 += 32; ag1 += 32; bg0 += 32; bg1 += 32;
    __syncthreads();                     // compiler drains vmcnt before barrier
    short8 af[4], bfr[4];
#pragma unroll
    for (int mi = 0; mi < 4; ++mi)
      af[mi] = *(const short8*)((const char*)As + (size_t)(wr * 64 + mi * 16 + l16) * 64 + quad * 16);
#pragma unroll
    for (int ni = 0; ni < 4; ++ni)
      bfr[ni] = *(const short8*)((const char*)Bs + (size_t)(wc * 64 + ni * 16 + l16) * 64 + quad * 16);
#pragma unroll
    for (int mi = 0; mi < 4; ++mi)
#pragma unroll
      for (int ni = 0; ni < 4; ++ni)
        acc[mi][ni] = __builtin_amdgcn_mfma_f32_16x16x32_bf16(af[mi], bfr[ni], acc[mi][ni], 0, 0, 0);
  }
  // ---- epilogue ----
  bf16* outb = nullptr; float* outf = nullptr;
  int colbase = 0, stride = 0;
  if constexpr (MODE == 0) {
    if (bn < 512)      { outb = (bf16*)O0; colbase = bn;       stride = 512; }
    else if (bn < 768) { outb = (bf16*)O1; colbase = bn - 512; stride = 256; }
    else               { outb = (bf16*)O2; colbase = bn - 768; stride = 256; }
  } else if constexpr (MODE == 1) {
    outb = (bf16*)O0; colbase = bn; stride = 512;
  } else {
    outf = (float*)O0; colbase = bn; stride = 1024;
  }
#pragma unroll
  for (int mi = 0; mi < 4; ++mi)
#pragma unroll
    for (int ni = 0; ni < 4; ++ni) {
      int row0 = bm + wr * 64 + mi * 16 + quad * 4;
      int col = colbase + wc * 64 + ni * 16 + l16;
#pragma unroll
      for (int r = 0; r < 4; ++r) {
        size_t off = (size_t)(row0 + r) * stride + col;
        if constexpr (MODE == 2) outf[off] = acc[mi][ni][r];
        else                     outb[off] = __float2bfloat16(acc[mi][ni][r]);
      }
    }
}

// ------- RMSnorm + RoPE (+q_gain, +1/sqrt(D)) -> packed Qp[b][8][2112][64], Kp[b][4][2112][64]
__global__ __launch_bounds__(256) void norm_rope_pack(const bf16* __restrict__ QB,
                                                      const bf16* __restrict__ KB,
                                                      const float* __restrict__ q_gain,
                                                      bf16* __restrict__ Qp, bf16* __restrict__ Kp) {
  int job = blockIdx.x * 4 + (threadIdx.x >> 6);
  if (job >= kB * kTP * 12) return;
  int lane = threadIdx.x & 63;
  int slot = job % 12, rowp = job / 12;
  int b = rowp / kTP, te = rowp % kTP;
  bf16* dst = (slot < 8) ? Qp + (((size_t)(b * 8 + slot)) * kTP + te) * 64 + lane
                         : Kp + (((size_t)(b * 4 + slot - 8)) * kTP + te) * 64 + lane;
  if (te >= kTEXT) { *dst = __float2bfloat16(0.f); return; }
  const bf16* src = (slot < 8) ? QB + ((size_t)(b * kTEXT + te)) * 512 + slot * 64 + lane
                               : KB + ((size_t)(b * kTEXT + te)) * 256 + (slot - 8) * 64 + lane;
  float v = __bfloat162float(*src);
  float ss = v * v;
#pragma unroll
  for (int o = 32; o > 0; o >>= 1) ss += __shfl_xor(ss, o, 64);
  float vn = v * (1.f / sqrtf(ss * (1.f / 64.f) + 1e-6f));
  float p = __shfl_xor(vn, 32, 64);
  float ang = (float)te * exp2f(-13.287712379549449f * (float)(lane & 31) * (1.f / 32.f));
  float c = cosf(ang), s = sinf(ang);
  float outv = (lane < 32) ? (vn * c - p * s) : (p * s + vn * c);
  float gain = (slot < 8) ? q_gain[slot] * 0.125f : 1.f;
  *dst = __float2bfloat16(outv * gain);
}

// ------- V transpose: VB[row][256] -> Vt[b][kvh][64][2112] (zero pads), LDS-tiled -------
__global__ __launch_bounds__(256) void vrepack(const bf16* __restrict__ VB, bf16* __restrict__ Vt) {
  __shared__ short Ts[64][66];
  const int tt = blockIdx.x, kvh = blockIdx.y, b = blockIdx.z;
  const int tid = threadIdx.x;
#pragma unroll
  for (int r = 0; r < 2; ++r) {
    int e = r * 256 + tid, row = e >> 3, c8 = e & 7;
    int te = tt * 64 + row;
    uint4 val = {0u, 0u, 0u, 0u};
    if (te < kTEXT) val = *(const uint4*)(VB + ((size_t)(b * kTEXT + te)) * 256 + kvh * 64 + c8 * 8);
    union { uint4 u; short s[8]; } w; w.u = val;
#pragma unroll
    for (int i = 0; i < 8; ++i) Ts[row][c8 * 8 + i] = w.s[i];
  }
  __syncthreads();
#pragma unroll
  for (int r = 0; r < 2; ++r) {
    int e = r * 256 + tid, d = e >> 3, c8 = e & 7;
    union { uint4 u; short s[8]; } w;
#pragma unroll
    for (int i = 0; i < 8; ++i) w.s[i] = Ts[c8 * 8 + i][d];
    *(uint4*)(Vt + (((size_t)(b * 4 + kvh)) * 64 + d) * kTP + tt * 64 + c8 * 8) = w.u;
  }
}

// ---------------- MFMA causal flash attention (fixed-max softmax, S^T layout) ----------------
__global__ __launch_bounds__(256) void attn_mfma(const bf16* __restrict__ Qp,
                                                 const bf16* __restrict__ Kp,
                                                 const bf16* __restrict__ Vt,
                                                 const float* __restrict__ attn_scale,
                                                 bf16* __restrict__ Y) {
  __shared__ short Ks[64][72];        // K tile [key][d]
  __shared__ short Vs[64][72];        // V^T tile [d][key]
  __shared__ short Ps[4][16][72];     // per-wave P [q][key]
  const int qt = (kQT - 1) - blockIdx.x;   // longest first
  const int h = blockIdx.y, b = blockIdx.z;
  const int kvh = h >> 1;
  const int tid = threadIdx.x, wave = tid >> 6, lane = tid & 63;
  const int quad = lane >> 4, l16 = lane & 15;

  short8 qf[2];
  {
    const bf16* qrow = Qp + (((size_t)(b * 8 + h)) * kTP + qt * 64 + wave * 16 + l16) * 64 + quad * 8;
    qf[0] = *(const short8*)(qrow);
    qf[1] = *(const short8*)(qrow + 32);
  }
  short8 ones;
#pragma unroll
  for (int i = 0; i < 8; ++i) ones[i] = (short)0x3F80;   // bf16 1.0

  const bf16* kbase = Kp + ((size_t)(b * 4 + kvh)) * kTP * 64;
  const bf16* vbase = Vt + ((size_t)(b * 4 + kvh)) * 64 * kTP;

  f32x4 O[4] = {};
  f32x4 lacc = {};
  const int q_abs = qt * 64 + wave * 16 + l16;

  for (int kt = 0; kt <= qt; ++kt) {
    __syncthreads();
#pragma unroll
    for (int r = 0; r < 2; ++r) {
      int e = r * 256 + tid, row = e >> 3, c8 = e & 7;
      uint4 kv = *(const uint4*)(kbase + ((size_t)(kt * 64 + row)) * 64 + c8 * 8);
      *(uint4*)&Ks[row][c8 * 8] = kv;
      uint4 vv = *(const uint4*)(vbase + (size_t)row * kTP + kt * 64 + c8 * 8);
      *(uint4*)&Vs[row][c8 * 8] = vv;
    }
    __syncthreads();

    f32x4 st[4] = {};
#pragma unroll
    for (int nb = 0; nb < 4; ++nb) {
      short8 ak0 = *(const short8*)&Ks[nb * 16 + l16][quad * 8];
      st[nb] = __builtin_amdgcn_mfma_f32_16x16x32_bf16(ak0, qf[0], st[nb], 0, 0, 0);
      short8 ak1 = *(const short8*)&Ks[nb * 16 + l16][32 + quad * 8];
      st[nb] = __builtin_amdgcn_mfma_f32_16x16x32_bf16(ak1, qf[1], st[nb], 0, 0, 0);
    }
    if (kt == qt) {
      int key0 = kt * 64 + quad * 4;
#pragma unroll
      for (int nb = 0; nb < 4; ++nb)
#pragma unroll
        for (int rg = 0; rg < 4; ++rg)
          if (key0 + nb * 16 + rg > q_abs) st[nb][rg] = -1e30f;
    }
#pragma unroll
    for (int nb = 0; nb < 4; ++nb) {
      union { unsigned long long q; bf16 hh[4]; } pw;
#pragma unroll
      for (int rg = 0; rg < 4; ++rg) pw.hh[rg] = __float2bfloat16(__expf(st[nb][rg]));
      *(unsigned long long*)&Ps[wave][l16][nb * 16 + quad * 4] = pw.q;
    }
    short8 pf0 = *(const short8*)&Ps[wave][l16][quad * 8];
    short8 pf1 = *(const short8*)&Ps[wave][l16][32 + quad * 8];
    lacc = __builtin_amdgcn_mfma_f32_16x16x32_bf16(pf0, ones, lacc, 0, 0, 0);
    lacc = __builtin_amdgcn_mfma_f32_16x16x32_bf16(pf1, ones, lacc, 0, 0, 0);
#pragma unroll
    for (int db = 0; db < 4; ++db) {
      short8 bv0 = *(const short8*)&Vs[db * 16 + l16][quad * 8];
      O[db] = __builtin_amdgcn_mfma_f32_16x16x32_bf16(pf0, bv0, O[db], 0, 0, 0);
      short8 bv1 = *(const short8*)&Vs[db * 16 + l16][32 + quad * 8];
      O[db] = __builtin_amdgcn_mfma_f32_16x16x32_bf16(pf1, bv1, O[db], 0, 0, 0);
    }
  }
  float asc = attn_scale[0];
#pragma unroll
  for (int rg = 0; rg < 4; ++rg) {
    int te_q = qt * 64 + wave * 16 + quad * 4 + rg;
    if (te_q < kNMETA || te_q >= kTEXT) continue;
    float so = asc / fmaxf(lacc[rg], 1e-30f);
    bf16* dst = Y + ((size_t)(b * kT + te_q - kNMETA)) * kDIM + h * 64 + l16;
#pragma unroll
    for (int db = 0; db < 4; ++db) dst[db * 16] = __float2bfloat16(O[db][rg] * so);
  }
}

// ---------------- SSM prep via MFMA: per head h, [64 bt rows] x [48 = dt|B|C] ----------------
__global__ __launch_bounds__(256) void ssm_prep(const bf16* __restrict__ sx,
                                                const float* __restrict__ dtw, const float* __restrict__ dtb,
                                                const float* __restrict__ Bw, const float* __restrict__ Cw,
                                                const float* __restrict__ logA,
                                                float* __restrict__ la, float* __restrict__ u,
                                                float* __restrict__ Cc) {
  __shared__ short Xs[64][72];
  __shared__ short Ws[48][72];
  const int bm = blockIdx.x * 64, h = blockIdx.y;
  const int tid = threadIdx.x, wave = tid >> 6, lane = tid & 63;
  const int quad = lane >> 4, l16 = lane & 15;
#pragma unroll
  for (int is = 0; is < 2; ++is) {
    int e = is * 256 + tid;                 // 512 uint4 slots = 64 rows x 8
    int row = e >> 3, v = e & 7;
    uint4 val = *(const uint4*)(sx + ((size_t)(bm + row)) * 512 + h * 64 + v * 8);
    *(uint4*)&Xs[row][v * 8] = val;
  }
#pragma unroll
  for (int is = 0; is < 2; ++is) {
    int s = is * 256 + tid;                 // 384 uint4 slots = 48 rows x 8
    if (s < 384) {
      int row = s >> 3, v = s & 7;
      const float* src = (row < 16) ? dtw + ((size_t)(h * 16 + row)) * 64
                       : (row < 32) ? Bw + ((size_t)(h * 16 + row - 16)) * 64
                                    : Cw + ((size_t)(h * 16 + row - 32)) * 64;
      float4 a0 = ((const float4*)src)[v * 2];
      float4 a1 = ((const float4*)src)[v * 2 + 1];
      *(uint4*)&Ws[row][v * 8] = pack8(a0, a1);
    }
  }
  __syncthreads();
  short8 af0 = *(const short8*)&Xs[wave * 16 + l16][quad * 8];
  short8 af1 = *(const short8*)&Xs[wave * 16 + l16][32 + quad * 8];
  f32x4 acc[3] = {};
#pragma unroll
  for (int nb = 0; nb < 3; ++nb) {
    short8 b0 = *(const short8*)&Ws[nb * 16 + l16][quad * 8];
    acc[nb] = __builtin_amdgcn_mfma_f32_16x16x32_bf16(af0, b0, acc[nb], 0, 0, 0);
    short8 b1 = *(const short8*)&Ws[nb * 16 + l16][32 + quad * 8];
    acc[nb] = __builtin_amdgcn_mfma_f32_16x16x32_bf16(af1, b1, acc[nb], 0, 0, 0);
  }
  float dtb_v = dtb[h * 16 + l16];
  float A_v = fminf(-expf(logA[h * 16 + l16]), 10.f);
#pragma unroll
  for (int rg = 0; rg < 4; ++rg) {
    int bt = bm + wave * 16 + quad * 4 + rg;
    size_t ix = (size_t)bt * 128 + h * 16 + l16;
    float raw = acc[0][rg] + dtb_v;
    float sp = fmaxf(raw, 0.f) + log1pf(expf(-fabsf(raw)));   // stable softplus
    float dt = fminf(sp, 1.f);
    float lav = fminf(fmaxf(dt * A_v, -0.5f), 0.f);
    la[ix] = lav;
    u[ix] = acc[1][rg] * dt;
    Cc[ix] = acc[2][rg];
  }
}

__global__ __launch_bounds__(256) void ssm_scan1(const float* __restrict__ la, const float* __restrict__ u,
                                                 bf16* __restrict__ hloc, bf16* __restrict__ Pb,
                                                 float* __restrict__ chH, float* __restrict__ chP) {
  int id = blockIdx.x * 256 + threadIdx.x;
  if (id >= 8192) return;
  int hs = id & 127, c = (id >> 7) & 31, b = id >> 12;
  float hv = 0.f, cum = 0.f;
  size_t base = ((size_t)b * kT) * 128 + hs;
  for (int i = 0; i < 64; ++i) {
    size_t ix = base + (size_t)(c * 64 + i) * 128;
    float lav = la[ix], uv = u[ix];
    cum += lav;
    hv = expf(lav) * hv + uv;
    hloc[ix] = __float2bfloat16(hv);
    Pb[ix] = __float2bfloat16(expf(fmaxf(cum, -30.f)));
  }
  chH[id] = hv;
  chP[id] = expf(fmaxf(cum, -30.f));
}

__global__ __launch_bounds__(256) void ssm_scan2(const float* __restrict__ chH,
                                                 const float* __restrict__ chP,
                                                 float* __restrict__ h0) {
  int id = threadIdx.x;
  int b = id >> 7, hs = id & 127;
  float h0v = 0.f;
  for (int c = 0; c < 32; ++c) {
    int ci = b * 4096 + c * 128 + hs;
    h0[ci] = h0v;
    h0v = chH[ci] + chP[ci] * h0v;
  }
}

__global__ __launch_bounds__(256) void ssm_out(const bf16* __restrict__ hloc, const bf16* __restrict__ Pb,
                                               const float* __restrict__ h0, const float* __restrict__ Cc,
                                               const bf16* __restrict__ sx, const float* __restrict__ Ow,
                                               const float* __restrict__ ssm_scale, bf16* __restrict__ Y) {
  int id = blockIdx.x * 256 + threadIdx.x;
  if (id >= kMX * 8) return;
  int h = id & 7, t = (id >> 3) & 2047, b = id >> 14;
  size_t ix0 = ((size_t)(b * kT + t)) * 128 + h * 16;
  int h0b = b * 4096 + (t >> 6) * 128 + h * 16;
  float hv[16], y = 0.f;
#pragma unroll
  for (int s = 0; s < 16; ++s) {
    float v = __bfloat162float(hloc[ix0 + s]) + __bfloat162float(Pb[ix0 + s]) * h0[h0b + s];
    hv[s] = v;
    y += Cc[ix0 + s] * v;
  }
  float x0 = __bfloat162float(sx[((size_t)(b * kT + t)) * 512 + h * 64]);
  float scl = ssm_scale[0];
  const float* ow = Ow + (size_t)h * 64 * 16;
  bf16* dst = Y + ((size_t)(b * kT + t)) * kDIM + 512 + h * 64;
  for (int d = 0; d < 64; ++d) {
    float acc = y * x0;
    const float* owr = ow + d * 16;
#pragma unroll
    for (int s = 0; s < 16; ++s) acc += hv[s] * owr[s];
    dst[d] = __float2bfloat16(acc * scl);
  }
}

// ---------------- host ----------------
extern "C" void kernel_launch(void* const* d_in, const int* in_sizes, int n_in,
                              void* d_out, int out_size, void* d_ws, size_t ws_size,
                              hipStream_t stream) {
  (void)in_sizes; (void)n_in; (void)out_size; (void)ws_size;
  const float* x        = (const float*)d_in[0];
  const float* meta     = (const float*)d_in[1];
  const float* c_q_w    = (const float*)d_in[2];
  const float* c_k_w    = (const float*)d_in[3];
  const float* c_v_w    = (const float*)d_in[4];
  const float* q_gain   = (const float*)d_in[5];
  const float* ssm_in_w = (const float*)d_in[6];
  const float* proj_w   = (const float*)d_in[7];
  const float* attn_sc  = (const float*)d_in[8];
  const float* ssm_sc   = (const float*)d_in[9];
  const float* ssm_logA = (const float*)d_in[10];
  const float* ssm_Bw   = (const float*)d_in[11];
  const float* ssm_Cw   = (const float*)d_in[12];
  const float* ssm_dtw  = (const float*)d_in[13];
  const float* ssm_dtb  = (const float*)d_in[14];
  const float* ssm_Ow   = (const float*)d_in[15];

  char* w = (char*)d_ws;
  bf16*  XE = (bf16*)(w + oXE);
  bf16*  QB = (bf16*)(w + oQB);
  bf16*  KB = (bf16*)(w + oKB);
  bf16*  VB = (bf16*)(w + oVB);
  bf16*  SX = (bf16*)(w + oSX);
  bf16*  YB = (bf16*)(w + oYB);
  bf16*  QP = (bf16*)(w + oQP);
  bf16*  KP = (bf16*)(w + oKP);
  bf16*  VT = (bf16*)(w + oVT);
  bf16*  WQ = (bf16*)(w + oWQ);
  bf16*  WS = (bf16*)(w + oWS);
  bf16*  WP = (bf16*)(w + oWP);
  float* LA = (float*)(w + oLA);
  float* UU = (float*)(w + oUU);
  float* CC = (float*)(w + oCC);
  bf16*  HL = (bf16*)(w + oHL);
  bf16*  PB = (bf16*)(w + oPB);
  float* CH = (float*)(w + oCH);
  float* CP = (float*)(w + oCP);
  float* H0 = (float*)(w + oH0);

  wconv<<<768, 256, 0, stream>>>(c_q_w, c_k_w, c_v_w, ssm_in_w, WQ, WS);
  build_xext<<<(kMPAD * 128 + 255) / 256, 256, 0, stream>>>(x, meta, XE);

  gemm128<0><<<dim3(8, kMPAD / 128), 256, 0, stream>>>(XE, WQ, QB, KB, VB);   // fused QKV
  gemm128<1><<<dim3(4, kMX / 128), 256, 0, stream>>>(XE, WS, SX, nullptr, nullptr);

  norm_rope_pack<<<(kB * kTP * 12) / 4, 256, 0, stream>>>(QB, KB, q_gain, QP, KP);
  vrepack<<<dim3(kQT, 4, kB), 256, 0, stream>>>(VB, VT);

  attn_mfma<<<dim3(kQT, 8, kB), 256, 0, stream>>>(QP, KP, VT, attn_sc, YB);

  ssm_prep<<<dim3(kMX / 64, 8), 256, 0, stream>>>(SX, ssm_dtw, ssm_dtb, ssm_Bw, ssm_Cw,
                                                  ssm_logA, LA, UU, CC);
  ssm_scan1<<<32, 256, 0, stream>>>(LA, UU, HL, PB, CH, CP);
  ssm_scan2<<<1, 256, 0, stream>>>(CH, CP, H0);
  ssm_out<<<(kMX * 8 + 255) / 256, 256, 0, stream>>>(HL, PB, H0, CC, SX, ssm_Ow, ssm_sc, YB);

  // proj weights -> bf16 into QP region (dead after attn), then 128-tile proj GEMM
  wcvt<<<512, 256, 0, stream>>>(proj_w, WP, 1024 * 128);
  gemm128<2><<<dim3(8, kMX / 128), 256, 0, stream>>>(YB, WP, d_out, nullptr, nullptr);
}